// Round 3
// baseline (65.645 us; speedup 1.0000x reference)
//
#include <hip/hip_runtime.h>

#define NPIX 16384

typedef __attribute__((ext_vector_type(8))) short short8;
typedef __attribute__((ext_vector_type(4))) float f32x4;

__device__ __forceinline__ unsigned short f2bf(float f) {
    unsigned u = __float_as_uint(f);
    unsigned r = (u + 0x7fffu + ((u >> 16) & 1u)) >> 16;
    return (unsigned short)r;
}

#define GLOAD16(SRC, DST) \
    __builtin_amdgcn_global_load_lds( \
        (const __attribute__((address_space(1))) unsigned*)(SRC), \
        (__attribute__((address_space(3))) unsigned*)(DST), 16, 0, 0)

// ---------------------------------------------------------------------------
// prep_wt: build Wt[832][256] bf16 = transpose of the concatenated weight
// matrix [k=256][n=832] where n: 0-255 v_w | 256-399 qd_w | 400-471 qs_w |
// 472-543 qw_w | 544-575 zero-pad | 576-831 out_w.  64x64 LDS tiled
// transpose, all global accesses coalesced. Block 52 fills biasD[320].
// ---------------------------------------------------------------------------
__device__ __forceinline__ float wsrc(int k, int n,
    const float* v_w, const float* qd_w, const float* qs_w,
    const float* qw_w, const float* out_w)
{
    if (n < 256) return v_w[k * 256 + n];
    n -= 256;
    if (n < 144) return qd_w[k * 144 + n];
    n -= 144;
    if (n < 72)  return qs_w[k * 72 + n];
    n -= 72;
    if (n < 72)  return qw_w[k * 72 + n];
    n -= 72;
    if (n < 32)  return 0.f;
    return out_w[k * 256 + (n - 32)];
}

__global__ __launch_bounds__(256) void prep_wt(
    const float* __restrict__ v_w, const float* __restrict__ qd_w,
    const float* __restrict__ qs_w, const float* __restrict__ qw_w,
    const float* __restrict__ out_w, const float* __restrict__ qd_b,
    const float* __restrict__ qw_b,
    unsigned short* __restrict__ Wt, float* __restrict__ biasD)
{
    const int tid = threadIdx.x;
    if (blockIdx.x == 52) {
        for (int i = tid; i < 320; i += 256) {
            float bv = 0.f;
            if (i < 144)                  bv = qd_b[i];
            else if (i >= 216 && i < 288) bv = qw_b[i - 216];
            biasD[i] = bv;
        }
        return;
    }
    __shared__ float t[64][65];
    const int tn = blockIdx.x % 13;   // n tile (13 x 64 = 832)
    const int tk = blockIdx.x / 13;   // k tile (4 x 64 = 256)
    #pragma unroll
    for (int i = 0; i < 16; ++i) {
        const int idx = tid + i * 256;      // 0..4095
        const int r = idx >> 6;             // k within tile
        const int c = idx & 63;             // n within tile
        t[r][c] = wsrc(tk * 64 + r, tn * 64 + c, v_w, qd_w, qs_w, qw_w, out_w);
    }
    __syncthreads();
    #pragma unroll
    for (int i = 0; i < 8; ++i) {
        const int idx = tid + i * 256;      // 0..2047
        const int rn = idx >> 5;            // n within tile
        const int cc = idx & 31;            // k-pair within tile
        const unsigned pk = (unsigned)f2bf(t[cc * 2][rn])
                          | ((unsigned)f2bf(t[cc * 2 + 1][rn]) << 16);
        ((unsigned*)(Wt + (size_t)(tn * 64 + rn) * 256 + tk * 64))[cc] = pk;
    }
}

// ---------------------------------------------------------------------------
// gemm_proj: fused projection GEMM over x (f32, converted in-staging).
//   blockIdx.y = j (0..8): j<4 -> v output (bf16, [NPIX][256])
//                          j>=4 -> proj output (f32, [NPIX][320])
// B rows in Wt start at j*64 for both regions (v = rows 0-255, D = 256-575).
// 64x64 tile, 4 waves, full K=256 in LDS, XOR-swizzled granules.
// ---------------------------------------------------------------------------
__global__ __launch_bounds__(256) void gemm_proj(
    const float* __restrict__ x, const unsigned short* __restrict__ Wt,
    const float* __restrict__ v_b, const float* __restrict__ biasD,
    unsigned short* __restrict__ v_bf, float* __restrict__ proj)
{
    __shared__ unsigned short As[64 * 256];
    __shared__ unsigned short Bs[64 * 256];

    const int tid  = threadIdx.x;
    const int wid  = tid >> 6;
    const int lane = tid & 63;
    const int row0 = blockIdx.x * 64;
    const int j    = blockIdx.y;

    // B staging: global_load_lds, inverse-swizzled source
    const unsigned short* Bb = Wt + (size_t)(j * 64) * 256;
    const int rl = lane >> 5;
    const int gl = lane & 31;
    #pragma unroll
    for (int it = 0; it < 8; ++it) {
        const int rr  = wid * 16 + it * 2 + rl;
        const int gsw = gl ^ (rr & 7);
        GLOAD16(Bb + rr * 256 + gsw * 8, &Bs[(wid * 16 + it * 2) * 256]);
    }

    // A staging: f32 load -> bf16 convert -> swizzled ds_write
    const float* Ab = x + (size_t)row0 * 256;
    #pragma unroll
    for (int it = 0; it < 8; ++it) {
        const int idx = tid + it * 256;     // 0..2047
        const int r   = idx >> 5;           // row 0..63
        const int gg  = idx & 31;           // granule
        const float4 u0 = *(const float4*)(Ab + r * 256 + gg * 8);
        const float4 u1 = *(const float4*)(Ab + r * 256 + gg * 8 + 4);
        uint4 pk;
        pk.x = f2bf(u0.x) | ((unsigned)f2bf(u0.y) << 16);
        pk.y = f2bf(u0.z) | ((unsigned)f2bf(u0.w) << 16);
        pk.z = f2bf(u1.x) | ((unsigned)f2bf(u1.y) << 16);
        pk.w = f2bf(u1.z) | ((unsigned)f2bf(u1.w) << 16);
        *(uint4*)&As[r * 256 + (gg ^ (r & 7)) * 8] = pk;
    }
    asm volatile("s_waitcnt vmcnt(0)" ::: "memory");
    __syncthreads();

    f32x4 acc00 = {0,0,0,0}, acc01 = {0,0,0,0};
    f32x4 acc10 = {0,0,0,0}, acc11 = {0,0,0,0};

    const int wr = (wid >> 1) * 32;
    const int wc = (wid & 1) * 32;
    const int fr = lane & 15;
    const int fg = lane >> 4;

    const int ra0 = wr + fr, ra1 = ra0 + 16;
    const int rb0 = wc + fr, rb1 = rb0 + 16;
    const int sa  = ra0 & 7;
    const int sb  = rb0 & 7;

    #pragma unroll
    for (int t = 0; t < 8; ++t) {
        const int gran = t * 4 + fg;
        short8 a0 = *(const short8*)&As[ra0 * 256 + (gran ^ sa) * 8];
        short8 a1 = *(const short8*)&As[ra1 * 256 + (gran ^ sa) * 8];
        short8 b0 = *(const short8*)&Bs[rb0 * 256 + (gran ^ sb) * 8];
        short8 b1 = *(const short8*)&Bs[rb1 * 256 + (gran ^ sb) * 8];
        acc00 = __builtin_amdgcn_mfma_f32_16x16x32_bf16(a0, b0, acc00, 0, 0, 0);
        acc01 = __builtin_amdgcn_mfma_f32_16x16x32_bf16(a0, b1, acc01, 0, 0, 0);
        acc10 = __builtin_amdgcn_mfma_f32_16x16x32_bf16(a1, b0, acc10, 0, 0, 0);
        acc11 = __builtin_amdgcn_mfma_f32_16x16x32_bf16(a1, b1, acc11, 0, 0, 0);
    }

    if (j < 4) {
        const int colA = j * 64 + wc + fr;
        const int colB = colA + 16;
        const float biasA = v_b[colA];
        const float biasB = v_b[colB];
        #pragma unroll
        for (int jj = 0; jj < 4; ++jj) {
            const int r0a = row0 + wr + fg * 4 + jj;
            const int r1a = r0a + 16;
            v_bf[(size_t)r0a * 256 + colA] = f2bf(acc00[jj] + biasA);
            v_bf[(size_t)r0a * 256 + colB] = f2bf(acc01[jj] + biasB);
            v_bf[(size_t)r1a * 256 + colA] = f2bf(acc10[jj] + biasA);
            v_bf[(size_t)r1a * 256 + colB] = f2bf(acc11[jj] + biasB);
        }
    } else {
        const int colA = (j - 4) * 64 + wc + fr;
        const int colB = colA + 16;
        const float biasA = biasD[colA];
        const float biasB = biasD[colB];
        #pragma unroll
        for (int jj = 0; jj < 4; ++jj) {
            const int r0a = row0 + wr + fg * 4 + jj;
            const int r1a = r0a + 16;
            proj[(size_t)r0a * 320 + colA] = acc00[jj] + biasA;
            proj[(size_t)r0a * 320 + colB] = acc01[jj] + biasB;
            proj[(size_t)r1a * 320 + colA] = acc10[jj] + biasA;
            proj[(size_t)r1a * 320 + colB] = acc11[jj] + biasB;
        }
    }
}

// ---------------------------------------------------------------------------
// gemm_out: Y[M][256] = mid[M][256] @ WtO^T + out_b (f32 out). Same core,
// A staged bf16 via global_load_lds.
// ---------------------------------------------------------------------------
__global__ __launch_bounds__(256) void gemm_out(
    const unsigned short* __restrict__ A, const unsigned short* __restrict__ WtO,
    const float* __restrict__ bias, float* __restrict__ Y)
{
    __shared__ unsigned short As[64 * 256];
    __shared__ unsigned short Bs[64 * 256];

    const int tid  = threadIdx.x;
    const int wid  = tid >> 6;
    const int lane = tid & 63;
    const int row0 = blockIdx.x * 64;
    const int col0 = blockIdx.y * 64;

    const unsigned short* Ab = A   + (size_t)row0 * 256;
    const unsigned short* Bb = WtO + (size_t)col0 * 256;
    const int rl = lane >> 5;
    const int gl = lane & 31;

    #pragma unroll
    for (int it = 0; it < 8; ++it) {
        const int r   = wid * 16 + it * 2 + rl;
        const int gsw = gl ^ (r & 7);
        GLOAD16(Ab + r * 256 + gsw * 8, &As[(wid * 16 + it * 2) * 256]);
        GLOAD16(Bb + r * 256 + gsw * 8, &Bs[(wid * 16 + it * 2) * 256]);
    }
    asm volatile("s_waitcnt vmcnt(0)" ::: "memory");
    __syncthreads();

    f32x4 acc00 = {0,0,0,0}, acc01 = {0,0,0,0};
    f32x4 acc10 = {0,0,0,0}, acc11 = {0,0,0,0};

    const int wr = (wid >> 1) * 32;
    const int wc = (wid & 1) * 32;
    const int fr = lane & 15;
    const int fg = lane >> 4;

    const int ra0 = wr + fr, ra1 = ra0 + 16;
    const int rb0 = wc + fr, rb1 = rb0 + 16;
    const int sa  = ra0 & 7;
    const int sb  = rb0 & 7;

    #pragma unroll
    for (int t = 0; t < 8; ++t) {
        const int gran = t * 4 + fg;
        short8 a0 = *(const short8*)&As[ra0 * 256 + (gran ^ sa) * 8];
        short8 a1 = *(const short8*)&As[ra1 * 256 + (gran ^ sa) * 8];
        short8 b0 = *(const short8*)&Bs[rb0 * 256 + (gran ^ sb) * 8];
        short8 b1 = *(const short8*)&Bs[rb1 * 256 + (gran ^ sb) * 8];
        acc00 = __builtin_amdgcn_mfma_f32_16x16x32_bf16(a0, b0, acc00, 0, 0, 0);
        acc01 = __builtin_amdgcn_mfma_f32_16x16x32_bf16(a0, b1, acc01, 0, 0, 0);
        acc10 = __builtin_amdgcn_mfma_f32_16x16x32_bf16(a1, b0, acc10, 0, 0, 0);
        acc11 = __builtin_amdgcn_mfma_f32_16x16x32_bf16(a1, b1, acc11, 0, 0, 0);
    }

    const int colA = col0 + wc + fr;
    const int colB = colA + 16;
    const float biasA = bias[colA];
    const float biasB = bias[colB];
    #pragma unroll
    for (int jj = 0; jj < 4; ++jj) {
        const int r0a = row0 + wr + fg * 4 + jj;
        const int r1a = r0a + 16;
        Y[(size_t)r0a * 256 + colA] = acc00[jj] + biasA;
        Y[(size_t)r0a * 256 + colB] = acc01[jj] + biasB;
        Y[(size_t)r1a * 256 + colA] = acc10[jj] + biasA;
        Y[(size_t)r1a * 256 + colB] = acc11[jj] + biasB;
    }
}

// ---------------------------------------------------------------------------
// Sampler v3: block = 8 pixels x 256 threads.
// Phase 0: stage 8 proj rows (320 f32 each) into LDS, coalesced float4.
// Phase 1: 576 (pix,g,k) items -> 4 offsets + 4 folded weights in LDS.
// Phase 2: thread (p,g,q) gathers bf16x8 (16B) channels: 36 loads, 288 FMA.
// ---------------------------------------------------------------------------
__global__ __launch_bounds__(256) void dcn_sample3(
    const unsigned short* __restrict__ vbuf,  // [NPIX][256] bf16
    const float* __restrict__ proj,           // [NPIX][320]
    const float* __restrict__ prior,          // [K][2]
    const float* __restrict__ dscale,         // [G]
    unsigned short* __restrict__ mid)         // [NPIX][256] bf16
{
    __shared__ float projs[8 * 320];
    __shared__ int   offs[576 * 4];
    __shared__ float wts [576 * 4];

    const int tid  = threadIdx.x;
    const int pix0 = blockIdx.x * 8;

    for (int i = tid; i < 640; i += 256) {
        const int p = i / 80, c = i - p * 80;
        *(float4*)&projs[p * 320 + c * 4] =
            *(const float4*)&proj[(size_t)(pix0 + p) * 320 + c * 4];
    }
    __syncthreads();

    for (int it = tid; it < 576; it += 256) {
        const int p   = it / 72;
        const int rem = it - p * 72;
        const int g   = rem / 9;
        const int k   = rem - g * 9;
        const int pix = pix0 + p;
        const int b   = pix >> 12;
        const int hw  = pix & 4095;
        const int h   = hw >> 6, w = hw & 63;

        const float* row = &projs[p * 320];
        const float qdx = row[g * 18 + k * 2 + 0];
        const float qdy = row[g * 18 + k * 2 + 1];
        const float s   = row[144 + g * 9 + k] + dscale[g];
        const float wt  = row[216 + g * 9 + k];
        const float sig6 = 6.0f / (1.0f + __expf(-s));
        const float px = (float)w + (qdx + prior[k * 2 + 0]) * sig6;
        const float py = (float)h + (qdy + prior[k * 2 + 1]) * sig6;

        const float x0f = floorf(px), y0f = floorf(py);
        const int ix = (int)x0f, iy = (int)y0f;
        const float wx1 = px - x0f, wx0 = 1.f - wx1;
        const float wy1 = py - y0f, wy0 = 1.f - wy1;
        const int base_b = b << 12;

        #pragma unroll
        for (int tp = 0; tp < 4; ++tp) {
            const int yy = iy + (tp >> 1), xx = ix + (tp & 1);
            const bool valid = (yy >= 0) & (yy < 64) & (xx >= 0) & (xx < 64);
            const int yc = min(max(yy, 0), 63), xc = min(max(xx, 0), 63);
            const float wgt = wt * ((tp >> 1) ? wy1 : wy0) * ((tp & 1) ? wx1 : wx0);
            offs[it * 4 + tp] = ((base_b + yc * 64 + xc) << 8) + g * 32;
            wts [it * 4 + tp] = valid ? wgt : 0.f;
        }
    }
    __syncthreads();

    const int p  = tid >> 5;
    const int g  = (tid >> 2) & 7;
    const int q  = tid & 3;
    const int c0 = q * 8;
    const int item0 = p * 72 + g * 9;

    float a0=0.f,a1=0.f,a2=0.f,a3=0.f,a4=0.f,a5=0.f,a6=0.f,a7=0.f;
    #pragma unroll
    for (int k = 0; k < 9; ++k) {
        const int it4 = (item0 + k) * 4;
        const int4   o4 = *(const int4*)&offs[it4];
        const float4 w4 = *(const float4*)&wts[it4];
        #pragma unroll
        for (int tp = 0; tp < 4; ++tp) {
            const int   off = (tp == 0) ? o4.x : (tp == 1) ? o4.y : (tp == 2) ? o4.z : o4.w;
            const float wgt = (tp == 0) ? w4.x : (tp == 1) ? w4.y : (tp == 2) ? w4.z : w4.w;
            const uint4 r = *(const uint4*)(vbuf + off + c0);
            a0 = fmaf(wgt, __uint_as_float(r.x << 16),          a0);
            a1 = fmaf(wgt, __uint_as_float(r.x & 0xffff0000u), a1);
            a2 = fmaf(wgt, __uint_as_float(r.y << 16),          a2);
            a3 = fmaf(wgt, __uint_as_float(r.y & 0xffff0000u), a3);
            a4 = fmaf(wgt, __uint_as_float(r.z << 16),          a4);
            a5 = fmaf(wgt, __uint_as_float(r.z & 0xffff0000u), a5);
            a6 = fmaf(wgt, __uint_as_float(r.w << 16),          a6);
            a7 = fmaf(wgt, __uint_as_float(r.w & 0xffff0000u), a7);
        }
    }

    const int pix = pix0 + p;
    unsigned short* mp = mid + (size_t)pix * 256 + g * 32 + c0;
    uint4 o;
    o.x = f2bf(a0) | ((unsigned)f2bf(a1) << 16);
    o.y = f2bf(a2) | ((unsigned)f2bf(a3) << 16);
    o.z = f2bf(a4) | ((unsigned)f2bf(a5) << 16);
    o.w = f2bf(a6) | ((unsigned)f2bf(a7) << 16);
    *(uint4*)mp = o;
}

// ---------------------------------------------------------------------------
extern "C" void kernel_launch(void* const* d_in, const int* in_sizes, int n_in,
                              void* d_out, int out_size, void* d_ws, size_t ws_size,
                              hipStream_t stream)
{
    (void)in_sizes; (void)n_in; (void)out_size; (void)ws_size;

    const float* x      = (const float*)d_in[0];
    const float* v_w    = (const float*)d_in[1];
    const float* v_b    = (const float*)d_in[2];
    const float* qd_w   = (const float*)d_in[3];
    const float* qd_b   = (const float*)d_in[4];
    const float* qs_w   = (const float*)d_in[5];
    const float* qw_w   = (const float*)d_in[6];
    const float* qw_b   = (const float*)d_in[7];
    const float* out_w  = (const float*)d_in[8];
    const float* out_b  = (const float*)d_in[9];
    const float* prior  = (const float*)d_in[10];
    const float* dscale = (const float*)d_in[11];
    float* out = (float*)d_out;

    char* ws = (char*)d_ws;
    unsigned short* v_bf  = (unsigned short*)(ws);                    // 8 MB
    float*          proj  = (float*)(ws + 8388608);                   // 21 MB
    unsigned short* mid   = (unsigned short*)(ws + 29360128);         // 8 MB
    unsigned short* Wt    = (unsigned short*)(ws + 37748736);         // 416 KB
    float*          biasD = (float*)(ws + 38175744);                  // 1.25 KB

    prep_wt<<<dim3(53), dim3(256), 0, stream>>>(v_w, qd_w, qs_w, qw_w, out_w,
                                                qd_b, qw_b, Wt, biasD);

    gemm_proj<<<dim3(256, 9), dim3(256), 0, stream>>>(x, Wt, v_b, biasD, v_bf, proj);

    dcn_sample3<<<dim3(NPIX / 8), dim3(256), 0, stream>>>(v_bf, proj, prior, dscale, mid);

    gemm_out<<<dim3(256, 4), dim3(256), 0, stream>>>(mid, Wt + 576 * 256, out_b, out);
}

// Round 4
// 58.247 us; speedup vs baseline: 1.1270x; 1.1270x over previous
//
#include <hip/hip_runtime.h>

#define NPIX 16384

typedef __attribute__((ext_vector_type(8))) short short8;
typedef __attribute__((ext_vector_type(4))) float f32x4;

__device__ __forceinline__ unsigned short f2bf(float f) {
    unsigned u = __float_as_uint(f);
    unsigned r = (u + 0x7fffu + ((u >> 16) & 1u)) >> 16;
    return (unsigned short)r;
}

#define GLOAD16(SRC, DST) \
    __builtin_amdgcn_global_load_lds( \
        (const __attribute__((address_space(1))) unsigned*)(SRC), \
        (__attribute__((address_space(3))) unsigned*)(DST), 16, 0, 0)

// ---------------------------------------------------------------------------
// prep_all: one dispatch for all preprocessing.
//   blocks 0..2047   : x f32 -> bf16 (8 elems/thread)
//   blocks 2048..2099: Wt[832][256] bf16 transpose tiles (coalesced via LDS)
//   block  2100      : biasD[320]
// Wt n-rows: 0-255 v_w | 256-399 qd_w | 400-471 qs_w | 472-543 qw_w |
//            544-575 zero | 576-831 out_w.
// ---------------------------------------------------------------------------
__device__ __forceinline__ float wsrc(int k, int n,
    const float* v_w, const float* qd_w, const float* qs_w,
    const float* qw_w, const float* out_w)
{
    if (n < 256) return v_w[k * 256 + n];
    n -= 256;
    if (n < 144) return qd_w[k * 144 + n];
    n -= 144;
    if (n < 72)  return qs_w[k * 72 + n];
    n -= 72;
    if (n < 72)  return qw_w[k * 72 + n];
    n -= 72;
    if (n < 32)  return 0.f;
    return out_w[k * 256 + (n - 32)];
}

__global__ __launch_bounds__(256) void prep_all(
    const float* __restrict__ x, unsigned short* __restrict__ xb,
    const float* __restrict__ v_w, const float* __restrict__ qd_w,
    const float* __restrict__ qs_w, const float* __restrict__ qw_w,
    const float* __restrict__ out_w, const float* __restrict__ qd_b,
    const float* __restrict__ qw_b,
    unsigned short* __restrict__ Wt, float* __restrict__ biasD)
{
    __shared__ float t[64][65];
    const int bid = blockIdx.x;
    const int tid = threadIdx.x;

    if (bid < 2048) {
        const size_t i = (size_t)bid * 256 + tid;
        const float4 v0 = *(const float4*)(x + i * 8);
        const float4 v1 = *(const float4*)(x + i * 8 + 4);
        uint4 pk;
        pk.x = f2bf(v0.x) | ((unsigned)f2bf(v0.y) << 16);
        pk.y = f2bf(v0.z) | ((unsigned)f2bf(v0.w) << 16);
        pk.z = f2bf(v1.x) | ((unsigned)f2bf(v1.y) << 16);
        pk.w = f2bf(v1.z) | ((unsigned)f2bf(v1.w) << 16);
        *(uint4*)(xb + i * 8) = pk;
        return;
    }
    if (bid == 2100) {
        for (int i = tid; i < 320; i += 256) {
            float bv = 0.f;
            if (i < 144)                  bv = qd_b[i];
            else if (i >= 216 && i < 288) bv = qw_b[i - 216];
            biasD[i] = bv;
        }
        return;
    }
    const int tile = bid - 2048;          // 0..51
    const int tn = tile % 13;
    const int tk = tile / 13;
    #pragma unroll
    for (int i = 0; i < 16; ++i) {
        const int idx = tid + i * 256;
        const int r = idx >> 6;
        const int c = idx & 63;
        t[r][c] = wsrc(tk * 64 + r, tn * 64 + c, v_w, qd_w, qs_w, qw_w, out_w);
    }
    __syncthreads();
    #pragma unroll
    for (int i = 0; i < 8; ++i) {
        const int idx = tid + i * 256;
        const int rn = idx >> 5;
        const int cc = idx & 31;
        const unsigned pk = (unsigned)f2bf(t[cc * 2][rn])
                          | ((unsigned)f2bf(t[cc * 2 + 1][rn]) << 16);
        ((unsigned*)(Wt + (size_t)(tn * 64 + rn) * 256 + tk * 64))[cc] = pk;
    }
}

// ---------------------------------------------------------------------------
// gemm_proj: [NPIX][256]bf16 @ Wt[j*64..][256]^T, j=0..8.
//   j<4  -> v_bf bf16 in GROUP-MAJOR layout [b][g][4096][32]
//   j>=4 -> proj f32 [NPIX][320]
// 64x64 tile, 4 waves, full K=256 in LDS, XOR-swizzled, global_load_lds.
// ---------------------------------------------------------------------------
__global__ __launch_bounds__(256) void gemm_proj(
    const unsigned short* __restrict__ A, const unsigned short* __restrict__ Wt,
    const float* __restrict__ v_b, const float* __restrict__ biasD,
    unsigned short* __restrict__ v_bf, float* __restrict__ proj)
{
    __shared__ unsigned short As[64 * 256];
    __shared__ unsigned short Bs[64 * 256];

    const int tid  = threadIdx.x;
    const int wid  = tid >> 6;
    const int lane = tid & 63;
    const int row0 = blockIdx.x * 64;
    const int j    = blockIdx.y;

    const unsigned short* Ab = A  + (size_t)row0 * 256;
    const unsigned short* Bb = Wt + (size_t)(j * 64) * 256;
    const int rl = lane >> 5;
    const int gl = lane & 31;

    #pragma unroll
    for (int it = 0; it < 8; ++it) {
        const int r   = wid * 16 + it * 2 + rl;
        const int gsw = gl ^ (r & 7);
        GLOAD16(Ab + r * 256 + gsw * 8, &As[(wid * 16 + it * 2) * 256]);
        GLOAD16(Bb + r * 256 + gsw * 8, &Bs[(wid * 16 + it * 2) * 256]);
    }
    asm volatile("s_waitcnt vmcnt(0)" ::: "memory");
    __syncthreads();

    f32x4 acc00 = {0,0,0,0}, acc01 = {0,0,0,0};
    f32x4 acc10 = {0,0,0,0}, acc11 = {0,0,0,0};

    const int wr = (wid >> 1) * 32;
    const int wc = (wid & 1) * 32;
    const int fr = lane & 15;
    const int fg = lane >> 4;

    const int ra0 = wr + fr, ra1 = ra0 + 16;
    const int rb0 = wc + fr, rb1 = rb0 + 16;
    const int sa  = ra0 & 7;
    const int sb  = rb0 & 7;

    #pragma unroll
    for (int t = 0; t < 8; ++t) {
        const int gran = t * 4 + fg;
        short8 a0 = *(const short8*)&As[ra0 * 256 + (gran ^ sa) * 8];
        short8 a1 = *(const short8*)&As[ra1 * 256 + (gran ^ sa) * 8];
        short8 b0 = *(const short8*)&Bs[rb0 * 256 + (gran ^ sb) * 8];
        short8 b1 = *(const short8*)&Bs[rb1 * 256 + (gran ^ sb) * 8];
        acc00 = __builtin_amdgcn_mfma_f32_16x16x32_bf16(a0, b0, acc00, 0, 0, 0);
        acc01 = __builtin_amdgcn_mfma_f32_16x16x32_bf16(a0, b1, acc01, 0, 0, 0);
        acc10 = __builtin_amdgcn_mfma_f32_16x16x32_bf16(a1, b0, acc10, 0, 0, 0);
        acc11 = __builtin_amdgcn_mfma_f32_16x16x32_bf16(a1, b1, acc11, 0, 0, 0);
    }

    if (j < 4) {
        const int colA = j * 64 + wc + fr;   // 0..255
        const int colB = colA + 16;
        const int gA = colA >> 5, cA = colA & 31;
        const int gB = colB >> 5, cB = colB & 31;
        const float biasA = v_b[colA];
        const float biasB = v_b[colB];
        #pragma unroll
        for (int jj = 0; jj < 4; ++jj) {
            const int r0a = row0 + wr + fg * 4 + jj;
            const int r1a = r0a + 16;
            const int b0i = r0a >> 12;       // same batch for r1a (tile-aligned)
            const int hw0 = r0a & 4095, hw1 = r1a & 4095;
            v_bf[((size_t)(b0i * 8 + gA) * 4096 + hw0) * 32 + cA] = f2bf(acc00[jj] + biasA);
            v_bf[((size_t)(b0i * 8 + gB) * 4096 + hw0) * 32 + cB] = f2bf(acc01[jj] + biasB);
            v_bf[((size_t)(b0i * 8 + gA) * 4096 + hw1) * 32 + cA] = f2bf(acc10[jj] + biasA);
            v_bf[((size_t)(b0i * 8 + gB) * 4096 + hw1) * 32 + cB] = f2bf(acc11[jj] + biasB);
        }
    } else {
        const int colA = (j - 4) * 64 + wc + fr;
        const int colB = colA + 16;
        const float biasA = biasD[colA];
        const float biasB = biasD[colB];
        #pragma unroll
        for (int jj = 0; jj < 4; ++jj) {
            const int r0a = row0 + wr + fg * 4 + jj;
            const int r1a = r0a + 16;
            proj[(size_t)r0a * 320 + colA] = acc00[jj] + biasA;
            proj[(size_t)r0a * 320 + colB] = acc01[jj] + biasB;
            proj[(size_t)r1a * 320 + colA] = acc10[jj] + biasA;
            proj[(size_t)r1a * 320 + colB] = acc11[jj] + biasB;
        }
    }
}

// ---------------------------------------------------------------------------
// gemm_out: out[M][256] = mid[M][256] @ WtO^T + out_b (f32).
// ---------------------------------------------------------------------------
__global__ __launch_bounds__(256) void gemm_out(
    const unsigned short* __restrict__ A, const unsigned short* __restrict__ WtO,
    const float* __restrict__ bias, float* __restrict__ Y)
{
    __shared__ unsigned short As[64 * 256];
    __shared__ unsigned short Bs[64 * 256];

    const int tid  = threadIdx.x;
    const int wid  = tid >> 6;
    const int lane = tid & 63;
    const int row0 = blockIdx.x * 64;
    const int col0 = blockIdx.y * 64;

    const unsigned short* Ab = A   + (size_t)row0 * 256;
    const unsigned short* Bb = WtO + (size_t)col0 * 256;
    const int rl = lane >> 5;
    const int gl = lane & 31;

    #pragma unroll
    for (int it = 0; it < 8; ++it) {
        const int r   = wid * 16 + it * 2 + rl;
        const int gsw = gl ^ (r & 7);
        GLOAD16(Ab + r * 256 + gsw * 8, &As[(wid * 16 + it * 2) * 256]);
        GLOAD16(Bb + r * 256 + gsw * 8, &Bs[(wid * 16 + it * 2) * 256]);
    }
    asm volatile("s_waitcnt vmcnt(0)" ::: "memory");
    __syncthreads();

    f32x4 acc00 = {0,0,0,0}, acc01 = {0,0,0,0};
    f32x4 acc10 = {0,0,0,0}, acc11 = {0,0,0,0};

    const int wr = (wid >> 1) * 32;
    const int wc = (wid & 1) * 32;
    const int fr = lane & 15;
    const int fg = lane >> 4;

    const int ra0 = wr + fr, ra1 = ra0 + 16;
    const int rb0 = wc + fr, rb1 = rb0 + 16;
    const int sa  = ra0 & 7;
    const int sb  = rb0 & 7;

    #pragma unroll
    for (int t = 0; t < 8; ++t) {
        const int gran = t * 4 + fg;
        short8 a0 = *(const short8*)&As[ra0 * 256 + (gran ^ sa) * 8];
        short8 a1 = *(const short8*)&As[ra1 * 256 + (gran ^ sa) * 8];
        short8 b0 = *(const short8*)&Bs[rb0 * 256 + (gran ^ sb) * 8];
        short8 b1 = *(const short8*)&Bs[rb1 * 256 + (gran ^ sb) * 8];
        acc00 = __builtin_amdgcn_mfma_f32_16x16x32_bf16(a0, b0, acc00, 0, 0, 0);
        acc01 = __builtin_amdgcn_mfma_f32_16x16x32_bf16(a0, b1, acc01, 0, 0, 0);
        acc10 = __builtin_amdgcn_mfma_f32_16x16x32_bf16(a1, b0, acc10, 0, 0, 0);
        acc11 = __builtin_amdgcn_mfma_f32_16x16x32_bf16(a1, b1, acc11, 0, 0, 0);
    }

    const int colA = col0 + wc + fr;
    const int colB = colA + 16;
    const float biasA = bias[colA];
    const float biasB = bias[colB];
    #pragma unroll
    for (int jj = 0; jj < 4; ++jj) {
        const int r0a = row0 + wr + fg * 4 + jj;
        const int r1a = r0a + 16;
        Y[(size_t)r0a * 256 + colA] = acc00[jj] + biasA;
        Y[(size_t)r0a * 256 + colB] = acc01[jj] + biasB;
        Y[(size_t)r1a * 256 + colA] = acc10[jj] + biasA;
        Y[(size_t)r1a * 256 + colB] = acc11[jj] + biasB;
    }
}

// ---------------------------------------------------------------------------
// Sampler v4: 8 pixels/block, group-major v layout, XCD-swizzled blocks.
// Phase 0: stage 8 proj rows into LDS (coalesced float4).
// Phase 1: 576 (pix,g,k) items -> 4 offsets + 4 folded weights in LDS.
// Phase 2: thread (p,g,q) gathers bf16x8 (16B): 36 loads, 288 FMA.
// ---------------------------------------------------------------------------
__global__ __launch_bounds__(256) void dcn_sample4(
    const unsigned short* __restrict__ vbuf,  // [4][8][4096][32] bf16
    const float* __restrict__ proj,           // [NPIX][320]
    const float* __restrict__ prior,          // [K][2]
    const float* __restrict__ dscale,         // [G]
    unsigned short* __restrict__ mid)         // [NPIX][256] bf16
{
    __shared__ float projs[8 * 320];
    __shared__ int   offs[576 * 4];
    __shared__ float wts [576 * 4];

    const int tid = threadIdx.x;
    // bijective XCD swizzle: 2048 blocks = 8 XCDs x 256 contiguous chunks
    const int bid  = blockIdx.x;
    const int wg   = (bid & 7) * 256 + (bid >> 3);
    const int pix0 = wg * 8;

    for (int i = tid; i < 640; i += 256) {
        const int p = i / 80, c = i - p * 80;
        *(float4*)&projs[p * 320 + c * 4] =
            *(const float4*)&proj[(size_t)(pix0 + p) * 320 + c * 4];
    }
    __syncthreads();

    for (int it = tid; it < 576; it += 256) {
        const int p   = it / 72;
        const int rem = it - p * 72;
        const int g   = rem / 9;
        const int k   = rem - g * 9;
        const int pix = pix0 + p;
        const int b   = pix >> 12;
        const int hw  = pix & 4095;
        const int h   = hw >> 6, w = hw & 63;

        const float* row = &projs[p * 320];
        const float qdx = row[g * 18 + k * 2 + 0];
        const float qdy = row[g * 18 + k * 2 + 1];
        const float s   = row[144 + g * 9 + k] + dscale[g];
        const float wt  = row[216 + g * 9 + k];
        const float sig6 = 6.0f / (1.0f + __expf(-s));
        const float px = (float)w + (qdx + prior[k * 2 + 0]) * sig6;
        const float py = (float)h + (qdy + prior[k * 2 + 1]) * sig6;

        const float x0f = floorf(px), y0f = floorf(py);
        const int ix = (int)x0f, iy = (int)y0f;
        const float wx1 = px - x0f, wx0 = 1.f - wx1;
        const float wy1 = py - y0f, wy0 = 1.f - wy1;
        const int plane = (b * 8 + g) << 12;   // (b*8+g)*4096

        #pragma unroll
        for (int tp = 0; tp < 4; ++tp) {
            const int yy = iy + (tp >> 1), xx = ix + (tp & 1);
            const bool valid = (yy >= 0) & (yy < 64) & (xx >= 0) & (xx < 64);
            const int yc = min(max(yy, 0), 63), xc = min(max(xx, 0), 63);
            const float wgt = wt * ((tp >> 1) ? wy1 : wy0) * ((tp & 1) ? wx1 : wx0);
            offs[it * 4 + tp] = (plane + yc * 64 + xc) * 32;
            wts [it * 4 + tp] = valid ? wgt : 0.f;
        }
    }
    __syncthreads();

    const int p  = tid >> 5;
    const int g  = (tid >> 2) & 7;
    const int q  = tid & 3;
    const int c0 = q * 8;
    const int item0 = p * 72 + g * 9;

    float a0=0.f,a1=0.f,a2=0.f,a3=0.f,a4=0.f,a5=0.f,a6=0.f,a7=0.f;
    #pragma unroll
    for (int k = 0; k < 9; ++k) {
        const int it4 = (item0 + k) * 4;
        const int4   o4 = *(const int4*)&offs[it4];
        const float4 w4 = *(const float4*)&wts[it4];
        #pragma unroll
        for (int tp = 0; tp < 4; ++tp) {
            const int   off = (tp == 0) ? o4.x : (tp == 1) ? o4.y : (tp == 2) ? o4.z : o4.w;
            const float wgt = (tp == 0) ? w4.x : (tp == 1) ? w4.y : (tp == 2) ? w4.z : w4.w;
            const uint4 r = *(const uint4*)(vbuf + off + c0);
            a0 = fmaf(wgt, __uint_as_float(r.x << 16),          a0);
            a1 = fmaf(wgt, __uint_as_float(r.x & 0xffff0000u), a1);
            a2 = fmaf(wgt, __uint_as_float(r.y << 16),          a2);
            a3 = fmaf(wgt, __uint_as_float(r.y & 0xffff0000u), a3);
            a4 = fmaf(wgt, __uint_as_float(r.z << 16),          a4);
            a5 = fmaf(wgt, __uint_as_float(r.z & 0xffff0000u), a5);
            a6 = fmaf(wgt, __uint_as_float(r.w << 16),          a6);
            a7 = fmaf(wgt, __uint_as_float(r.w & 0xffff0000u), a7);
        }
    }

    const int pix = pix0 + p;
    unsigned short* mp = mid + (size_t)pix * 256 + g * 32 + c0;
    uint4 o;
    o.x = f2bf(a0) | ((unsigned)f2bf(a1) << 16);
    o.y = f2bf(a2) | ((unsigned)f2bf(a3) << 16);
    o.z = f2bf(a4) | ((unsigned)f2bf(a5) << 16);
    o.w = f2bf(a6) | ((unsigned)f2bf(a7) << 16);
    *(uint4*)mp = o;
}

// ---------------------------------------------------------------------------
extern "C" void kernel_launch(void* const* d_in, const int* in_sizes, int n_in,
                              void* d_out, int out_size, void* d_ws, size_t ws_size,
                              hipStream_t stream)
{
    (void)in_sizes; (void)n_in; (void)out_size; (void)ws_size;

    const float* x      = (const float*)d_in[0];
    const float* v_w    = (const float*)d_in[1];
    const float* v_b    = (const float*)d_in[2];
    const float* qd_w   = (const float*)d_in[3];
    const float* qd_b   = (const float*)d_in[4];
    const float* qs_w   = (const float*)d_in[5];
    const float* qw_w   = (const float*)d_in[6];
    const float* qw_b   = (const float*)d_in[7];
    const float* out_w  = (const float*)d_in[8];
    const float* out_b  = (const float*)d_in[9];
    const float* prior  = (const float*)d_in[10];
    const float* dscale = (const float*)d_in[11];
    float* out = (float*)d_out;

    char* ws = (char*)d_ws;
    unsigned short* xb    = (unsigned short*)(ws);                    // 8 MB
    unsigned short* v_bf  = (unsigned short*)(ws + 8388608);          // 8 MB
    float*          proj  = (float*)(ws + 16777216);                  // 21 MB
    unsigned short* mid   = (unsigned short*)(ws + 37748736);         // 8 MB
    unsigned short* Wt    = (unsigned short*)(ws + 46137344);         // 416 KB
    float*          biasD = (float*)(ws + 46563328);                  // 1.25 KB

    prep_all<<<dim3(2101), dim3(256), 0, stream>>>(x, xb, v_w, qd_w, qs_w, qw_w,
                                                   out_w, qd_b, qw_b, Wt, biasD);

    gemm_proj<<<dim3(256, 9), dim3(256), 0, stream>>>(xb, Wt, v_b, biasD, v_bf, proj);

    dcn_sample4<<<dim3(NPIX / 8), dim3(256), 0, stream>>>(v_bf, proj, prior, dscale, mid);

    gemm_out<<<dim3(256, 4), dim3(256), 0, stream>>>(mid, Wt + 576 * 256, out_b, out);
}

// Round 6
// 57.980 us; speedup vs baseline: 1.1322x; 1.0046x over previous
//
#include <hip/hip_runtime.h>

#define NPIX 16384

typedef __attribute__((ext_vector_type(8))) short short8;
typedef __attribute__((ext_vector_type(4))) float f32x4;

__device__ __forceinline__ unsigned short f2bf(float f) {
    unsigned u = __float_as_uint(f);
    unsigned r = (u + 0x7fffu + ((u >> 16) & 1u)) >> 16;
    return (unsigned short)r;
}

#define GLOAD16(SRC, DST) \
    __builtin_amdgcn_global_load_lds( \
        (const __attribute__((address_space(1))) unsigned*)(SRC), \
        (__attribute__((address_space(3))) unsigned*)(DST), 16, 0, 0)

// ---------------------------------------------------------------------------
// prep_all: blocks 0..2047 x->bf16; 2048..2099 Wt transpose; 2100 biasD +
// v_bf guard pad (zeros; absorbs the one-pixel overrun of x-pair loads at
// the image corner).
// Wt n-rows: 0-255 v_w | 256-399 qd_w | 400-471 qs_w | 472-543 qw_w |
//            544-575 zero | 576-831 out_w.
// ---------------------------------------------------------------------------
__device__ __forceinline__ float wsrc(int k, int n,
    const float* v_w, const float* qd_w, const float* qs_w,
    const float* qw_w, const float* out_w)
{
    if (n < 256) return v_w[k * 256 + n];
    n -= 256;
    if (n < 144) return qd_w[k * 144 + n];
    n -= 144;
    if (n < 72)  return qs_w[k * 72 + n];
    n -= 72;
    if (n < 72)  return qw_w[k * 72 + n];
    n -= 72;
    if (n < 32)  return 0.f;
    return out_w[k * 256 + (n - 32)];
}

__global__ __launch_bounds__(256) void prep_all(
    const float* __restrict__ x, unsigned short* __restrict__ xb,
    const float* __restrict__ v_w, const float* __restrict__ qd_w,
    const float* __restrict__ qs_w, const float* __restrict__ qw_w,
    const float* __restrict__ out_w, const float* __restrict__ qd_b,
    const float* __restrict__ qw_b,
    unsigned short* __restrict__ Wt, float* __restrict__ biasD,
    unsigned short* __restrict__ vpad)
{
    __shared__ float t[64][65];
    const int bid = blockIdx.x;
    const int tid = threadIdx.x;

    if (bid < 2048) {
        const size_t i = (size_t)bid * 256 + tid;
        const float4 v0 = *(const float4*)(x + i * 8);
        const float4 v1 = *(const float4*)(x + i * 8 + 4);
        uint4 pk;
        pk.x = f2bf(v0.x) | ((unsigned)f2bf(v0.y) << 16);
        pk.y = f2bf(v0.z) | ((unsigned)f2bf(v0.w) << 16);
        pk.z = f2bf(v1.x) | ((unsigned)f2bf(v1.y) << 16);
        pk.w = f2bf(v1.z) | ((unsigned)f2bf(v1.w) << 16);
        *(uint4*)(xb + i * 8) = pk;
        return;
    }
    if (bid == 2100) {
        for (int i = tid; i < 320; i += 256) {
            float bv = 0.f;
            if (i < 144)                  bv = qd_b[i];
            else if (i >= 216 && i < 288) bv = qw_b[i - 216];
            biasD[i] = bv;
        }
        for (int i = tid; i < 512; i += 256) vpad[i] = 0;  // 1KB guard
        return;
    }
    const int tile = bid - 2048;
    const int tn = tile % 13;
    const int tk = tile / 13;
    #pragma unroll
    for (int i = 0; i < 16; ++i) {
        const int idx = tid + i * 256;
        const int r = idx >> 6;
        const int c = idx & 63;
        t[r][c] = wsrc(tk * 64 + r, tn * 64 + c, v_w, qd_w, qs_w, qw_w, out_w);
    }
    __syncthreads();
    #pragma unroll
    for (int i = 0; i < 8; ++i) {
        const int idx = tid + i * 256;
        const int rn = idx >> 5;
        const int cc = idx & 31;
        const unsigned pk = (unsigned)f2bf(t[cc * 2][rn])
                          | ((unsigned)f2bf(t[cc * 2 + 1][rn]) << 16);
        ((unsigned*)(Wt + (size_t)(tn * 64 + rn) * 256 + tk * 64))[cc] = pk;
    }
}

// ---------------------------------------------------------------------------
// gemm_proj: [NPIX][256]bf16 @ Wt[j*64..][256]^T, j=0..8.
//   j<4  -> v_bf bf16 GROUP-MAJOR [b][g][4096][32];  j>=4 -> proj f32 [NPIX][320]
// ---------------------------------------------------------------------------
__global__ __launch_bounds__(256) void gemm_proj(
    const unsigned short* __restrict__ A, const unsigned short* __restrict__ Wt,
    const float* __restrict__ v_b, const float* __restrict__ biasD,
    unsigned short* __restrict__ v_bf, float* __restrict__ proj)
{
    __shared__ unsigned short As[64 * 256];
    __shared__ unsigned short Bs[64 * 256];

    const int tid  = threadIdx.x;
    const int wid  = tid >> 6;
    const int lane = tid & 63;
    const int row0 = blockIdx.x * 64;
    const int j    = blockIdx.y;

    const unsigned short* Ab = A  + (size_t)row0 * 256;
    const unsigned short* Bb = Wt + (size_t)(j * 64) * 256;
    const int rl = lane >> 5;
    const int gl = lane & 31;

    #pragma unroll
    for (int it = 0; it < 8; ++it) {
        const int r   = wid * 16 + it * 2 + rl;
        const int gsw = gl ^ (r & 7);
        GLOAD16(Ab + r * 256 + gsw * 8, &As[(wid * 16 + it * 2) * 256]);
        GLOAD16(Bb + r * 256 + gsw * 8, &Bs[(wid * 16 + it * 2) * 256]);
    }
    asm volatile("s_waitcnt vmcnt(0)" ::: "memory");
    __syncthreads();

    f32x4 acc00 = {0,0,0,0}, acc01 = {0,0,0,0};
    f32x4 acc10 = {0,0,0,0}, acc11 = {0,0,0,0};

    const int wr = (wid >> 1) * 32;
    const int wc = (wid & 1) * 32;
    const int fr = lane & 15;
    const int fg = lane >> 4;

    const int ra0 = wr + fr, ra1 = ra0 + 16;
    const int rb0 = wc + fr, rb1 = rb0 + 16;
    const int sa  = ra0 & 7;
    const int sb  = rb0 & 7;

    #pragma unroll
    for (int t = 0; t < 8; ++t) {
        const int gran = t * 4 + fg;
        short8 a0 = *(const short8*)&As[ra0 * 256 + (gran ^ sa) * 8];
        short8 a1 = *(const short8*)&As[ra1 * 256 + (gran ^ sa) * 8];
        short8 b0 = *(const short8*)&Bs[rb0 * 256 + (gran ^ sb) * 8];
        short8 b1 = *(const short8*)&Bs[rb1 * 256 + (gran ^ sb) * 8];
        acc00 = __builtin_amdgcn_mfma_f32_16x16x32_bf16(a0, b0, acc00, 0, 0, 0);
        acc01 = __builtin_amdgcn_mfma_f32_16x16x32_bf16(a0, b1, acc01, 0, 0, 0);
        acc10 = __builtin_amdgcn_mfma_f32_16x16x32_bf16(a1, b0, acc10, 0, 0, 0);
        acc11 = __builtin_amdgcn_mfma_f32_16x16x32_bf16(a1, b1, acc11, 0, 0, 0);
    }

    if (j < 4) {
        const int colA = j * 64 + wc + fr;
        const int colB = colA + 16;
        const int gA = colA >> 5, cA = colA & 31;
        const int gB = colB >> 5, cB = colB & 31;
        const float biasA = v_b[colA];
        const float biasB = v_b[colB];
        #pragma unroll
        for (int jj = 0; jj < 4; ++jj) {
            const int r0a = row0 + wr + fg * 4 + jj;
            const int r1a = r0a + 16;
            const int b0i = r0a >> 12;
            const int hw0 = r0a & 4095, hw1 = r1a & 4095;
            v_bf[((size_t)(b0i * 8 + gA) * 4096 + hw0) * 32 + cA] = f2bf(acc00[jj] + biasA);
            v_bf[((size_t)(b0i * 8 + gB) * 4096 + hw0) * 32 + cB] = f2bf(acc01[jj] + biasB);
            v_bf[((size_t)(b0i * 8 + gA) * 4096 + hw1) * 32 + cA] = f2bf(acc10[jj] + biasA);
            v_bf[((size_t)(b0i * 8 + gB) * 4096 + hw1) * 32 + cB] = f2bf(acc11[jj] + biasB);
        }
    } else {
        const int colA = (j - 4) * 64 + wc + fr;
        const int colB = colA + 16;
        const float biasA = biasD[colA];
        const float biasB = biasD[colB];
        #pragma unroll
        for (int jj = 0; jj < 4; ++jj) {
            const int r0a = row0 + wr + fg * 4 + jj;
            const int r1a = r0a + 16;
            proj[(size_t)r0a * 320 + colA] = acc00[jj] + biasA;
            proj[(size_t)r0a * 320 + colB] = acc01[jj] + biasB;
            proj[(size_t)r1a * 320 + colA] = acc10[jj] + biasA;
            proj[(size_t)r1a * 320 + colB] = acc11[jj] + biasB;
        }
    }
}

// ---------------------------------------------------------------------------
// gemm_out: out[M][256] = mid[M][256] @ WtO^T + out_b (f32).
// ---------------------------------------------------------------------------
__global__ __launch_bounds__(256) void gemm_out(
    const unsigned short* __restrict__ A, const unsigned short* __restrict__ WtO,
    const float* __restrict__ bias, float* __restrict__ Y)
{
    __shared__ unsigned short As[64 * 256];
    __shared__ unsigned short Bs[64 * 256];

    const int tid  = threadIdx.x;
    const int wid  = tid >> 6;
    const int lane = tid & 63;
    const int row0 = blockIdx.x * 64;
    const int col0 = blockIdx.y * 64;

    const unsigned short* Ab = A   + (size_t)row0 * 256;
    const unsigned short* Bb = WtO + (size_t)col0 * 256;
    const int rl = lane >> 5;
    const int gl = lane & 31;

    #pragma unroll
    for (int it = 0; it < 8; ++it) {
        const int r   = wid * 16 + it * 2 + rl;
        const int gsw = gl ^ (r & 7);
        GLOAD16(Ab + r * 256 + gsw * 8, &As[(wid * 16 + it * 2) * 256]);
        GLOAD16(Bb + r * 256 + gsw * 8, &Bs[(wid * 16 + it * 2) * 256]);
    }
    asm volatile("s_waitcnt vmcnt(0)" ::: "memory");
    __syncthreads();

    f32x4 acc00 = {0,0,0,0}, acc01 = {0,0,0,0};
    f32x4 acc10 = {0,0,0,0}, acc11 = {0,0,0,0};

    const int wr = (wid >> 1) * 32;
    const int wc = (wid & 1) * 32;
    const int fr = lane & 15;
    const int fg = lane >> 4;

    const int ra0 = wr + fr, ra1 = ra0 + 16;
    const int rb0 = wc + fr, rb1 = rb0 + 16;
    const int sa  = ra0 & 7;
    const int sb  = rb0 & 7;

    #pragma unroll
    for (int t = 0; t < 8; ++t) {
        const int gran = t * 4 + fg;
        short8 a0 = *(const short8*)&As[ra0 * 256 + (gran ^ sa) * 8];
        short8 a1 = *(const short8*)&As[ra1 * 256 + (gran ^ sa) * 8];
        short8 b0 = *(const short8*)&Bs[rb0 * 256 + (gran ^ sb) * 8];
        short8 b1 = *(const short8*)&Bs[rb1 * 256 + (gran ^ sb) * 8];
        acc00 = __builtin_amdgcn_mfma_f32_16x16x32_bf16(a0, b0, acc00, 0, 0, 0);
        acc01 = __builtin_amdgcn_mfma_f32_16x16x32_bf16(a0, b1, acc01, 0, 0, 0);
        acc10 = __builtin_amdgcn_mfma_f32_16x16x32_bf16(a1, b0, acc10, 0, 0, 0);
        acc11 = __builtin_amdgcn_mfma_f32_16x16x32_bf16(a1, b1, acc11, 0, 0, 0);
    }

    const int colA = col0 + wc + fr;
    const int colB = colA + 16;
    const float biasA = bias[colA];
    const float biasB = bias[colB];
    #pragma unroll
    for (int jj = 0; jj < 4; ++jj) {
        const int r0a = row0 + wr + fg * 4 + jj;
        const int r1a = r0a + 16;
        Y[(size_t)r0a * 256 + colA] = acc00[jj] + biasA;
        Y[(size_t)r0a * 256 + colB] = acc01[jj] + biasB;
        Y[(size_t)r1a * 256 + colA] = acc10[jj] + biasA;
        Y[(size_t)r1a * 256 + colB] = acc11[jj] + biasB;
    }
}

// ---------------------------------------------------------------------------
// Sampler v5b: 4 pixels/block, 8 lanes per (pixel,group).
// Lane q: x-half xh=q>>2, channels (q&3)*8. Two 16B loads per k (row y0,
// row y1); the wave exposes each 128B x-pair span to the coalescer.
// __shfl_xor(4) merges x0/x0+1 partials. Address clamps keep the linear
// pixel index in [-1, 131071]; +1 overrun lands in the written guard pad,
// -1 lands in xb (finite bf16) -- weights are 0 there either way.
// ---------------------------------------------------------------------------
__global__ __launch_bounds__(256) void dcn_sample5(
    const unsigned short* __restrict__ vbuf,  // [4][8][4096][32] bf16
    const float* __restrict__ proj,           // [NPIX][320]
    const float* __restrict__ prior,          // [K][2]
    const float* __restrict__ dscale,         // [G]
    unsigned short* __restrict__ mid)         // [NPIX][256] bf16
{
    __shared__ float projs[4 * 320];
    __shared__ int   offs[288 * 2];
    __shared__ float wts [288 * 4];

    const int tid = threadIdx.x;
    // bijective XCD swizzle: 4096 blocks = 8 XCDs x 512 contiguous chunks
    const int bid  = blockIdx.x;
    const int wg   = (bid & 7) * 512 + (bid >> 3);
    const int pix0 = wg * 4;

    for (int i = tid; i < 320; i += 256) {
        const int p = i / 80, c = i - p * 80;
        *(float4*)&projs[p * 320 + c * 4] =
            *(const float4*)&proj[(size_t)(pix0 + p) * 320 + c * 4];
    }
    __syncthreads();

    for (int it = tid; it < 288; it += 256) {
        const int p   = it / 72;
        const int rem = it - p * 72;
        const int g   = rem / 9;
        const int k   = rem - g * 9;
        const int pix = pix0 + p;
        const int b   = pix >> 12;
        const int hw  = pix & 4095;
        const int h   = hw >> 6, w = hw & 63;

        const float* row = &projs[p * 320];
        const float qdx = row[g * 18 + k * 2 + 0];
        const float qdy = row[g * 18 + k * 2 + 1];
        const float s   = row[144 + g * 9 + k] + dscale[g];
        const float wt  = row[216 + g * 9 + k];
        const float sig6 = 6.0f / (1.0f + __expf(-s));
        const float px = (float)w + (qdx + prior[k * 2 + 0]) * sig6;
        const float py = (float)h + (qdy + prior[k * 2 + 1]) * sig6;

        const float x0f = floorf(px), y0f = floorf(py);
        const int ix = (int)x0f, iy = (int)y0f;
        const float wx1 = px - x0f, wx0 = 1.f - wx1;
        const float wy1 = py - y0f, wy0 = 1.f - wy1;
        const int plane = (b * 8 + g) << 12;

        // weights (validity folded in, decided by UNCLAMPED coords)
        #pragma unroll
        for (int tp = 0; tp < 4; ++tp) {
            const int yy = iy + (tp >> 1), xx = ix + (tp & 1);
            const bool valid = (yy >= 0) & (yy < 64) & (xx >= 0) & (xx < 64);
            const float wgt = wt * ((tp >> 1) ? wy1 : wy0) * ((tp & 1) ? wx1 : wx0);
            wts[it * 4 + tp] = valid ? wgt : 0.f;
        }
        // row base offsets: tight clamps keep reads inside vbuf (+guard)
        const int xs = min(max(ix, -1), 63);
        const int y0 = min(max(iy,     0), 63);
        const int y1 = min(max(iy + 1, 0), 63);
        offs[it * 2 + 0] = (plane + y0 * 64 + xs) * 32;
        offs[it * 2 + 1] = (plane + y1 * 64 + xs) * 32;
    }
    __syncthreads();

    const int p  = tid >> 6;          // pixel 0..3
    const int g  = (tid >> 3) & 7;    // group
    const int q  = tid & 7;           // lane-in-group
    const int xh = q >> 2;            // x-half: 0 -> x0, 1 -> x0+1
    const int cq = q & 3;             // channel quarter
    const int item0 = p * 72 + g * 9;

    float a0=0.f,a1=0.f,a2=0.f,a3=0.f,a4=0.f,a5=0.f,a6=0.f,a7=0.f;
    #pragma unroll
    for (int k = 0; k < 9; ++k) {
        const int it = item0 + k;
        const int2   o2 = *(const int2*)&offs[it * 2];
        const float  w0 = wts[it * 4 + xh];        // (y0, x_xh)
        const float  w1 = wts[it * 4 + 2 + xh];    // (y1, x_xh)
        const uint4 r0 = *(const uint4*)(vbuf + o2.x + q * 8);
        const uint4 r1 = *(const uint4*)(vbuf + o2.y + q * 8);
        a0 = fmaf(w0, __uint_as_float(r0.x << 16),          a0);
        a1 = fmaf(w0, __uint_as_float(r0.x & 0xffff0000u), a1);
        a2 = fmaf(w0, __uint_as_float(r0.y << 16),          a2);
        a3 = fmaf(w0, __uint_as_float(r0.y & 0xffff0000u), a3);
        a4 = fmaf(w0, __uint_as_float(r0.z << 16),          a4);
        a5 = fmaf(w0, __uint_as_float(r0.z & 0xffff0000u), a5);
        a6 = fmaf(w0, __uint_as_float(r0.w << 16),          a6);
        a7 = fmaf(w0, __uint_as_float(r0.w & 0xffff0000u), a7);
        a0 = fmaf(w1, __uint_as_float(r1.x << 16),          a0);
        a1 = fmaf(w1, __uint_as_float(r1.x & 0xffff0000u), a1);
        a2 = fmaf(w1, __uint_as_float(r1.y << 16),          a2);
        a3 = fmaf(w1, __uint_as_float(r1.y & 0xffff0000u), a3);
        a4 = fmaf(w1, __uint_as_float(r1.z << 16),          a4);
        a5 = fmaf(w1, __uint_as_float(r1.z & 0xffff0000u), a5);
        a6 = fmaf(w1, __uint_as_float(r1.w << 16),          a6);
        a7 = fmaf(w1, __uint_as_float(r1.w & 0xffff0000u), a7);
    }

    a0 += __shfl_xor(a0, 4);
    a1 += __shfl_xor(a1, 4);
    a2 += __shfl_xor(a2, 4);
    a3 += __shfl_xor(a3, 4);
    a4 += __shfl_xor(a4, 4);
    a5 += __shfl_xor(a5, 4);
    a6 += __shfl_xor(a6, 4);
    a7 += __shfl_xor(a7, 4);

    if (xh == 0) {
        const int pix = pix0 + p;
        unsigned short* mp = mid + (size_t)pix * 256 + g * 32 + cq * 8;
        uint4 o;
        o.x = f2bf(a0) | ((unsigned)f2bf(a1) << 16);
        o.y = f2bf(a2) | ((unsigned)f2bf(a3) << 16);
        o.z = f2bf(a4) | ((unsigned)f2bf(a5) << 16);
        o.w = f2bf(a6) | ((unsigned)f2bf(a7) << 16);
        *(uint4*)mp = o;
    }
}

// ---------------------------------------------------------------------------
extern "C" void kernel_launch(void* const* d_in, const int* in_sizes, int n_in,
                              void* d_out, int out_size, void* d_ws, size_t ws_size,
                              hipStream_t stream)
{
    (void)in_sizes; (void)n_in; (void)out_size; (void)ws_size;

    const float* x      = (const float*)d_in[0];
    const float* v_w    = (const float*)d_in[1];
    const float* v_b    = (const float*)d_in[2];
    const float* qd_w   = (const float*)d_in[3];
    const float* qd_b   = (const float*)d_in[4];
    const float* qs_w   = (const float*)d_in[5];
    const float* qw_w   = (const float*)d_in[6];
    const float* qw_b   = (const float*)d_in[7];
    const float* out_w  = (const float*)d_in[8];
    const float* out_b  = (const float*)d_in[9];
    const float* prior  = (const float*)d_in[10];
    const float* dscale = (const float*)d_in[11];
    float* out = (float*)d_out;

    char* ws = (char*)d_ws;
    unsigned short* xb    = (unsigned short*)(ws);                    // 8 MB
    unsigned short* v_bf  = (unsigned short*)(ws + 8388608);          // 8 MB
    unsigned short* vpad  = (unsigned short*)(ws + 16777216);         // 1 KB guard
    float*          proj  = (float*)(ws + 16778240);                  // 20.97 MB
    unsigned short* mid   = (unsigned short*)(ws + 37749760);         // 8 MB
    unsigned short* Wt    = (unsigned short*)(ws + 46138368);         // 416 KB
    float*          biasD = (float*)(ws + 46564352);                  // 1.25 KB

    prep_all<<<dim3(2101), dim3(256), 0, stream>>>(x, xb, v_w, qd_w, qs_w, qw_w,
                                                   out_w, qd_b, qw_b, Wt, biasD, vpad);

    gemm_proj<<<dim3(256, 9), dim3(256), 0, stream>>>(xb, Wt, v_b, biasD, v_bf, proj);

    dcn_sample5<<<dim3(NPIX / 4), dim3(256), 0, stream>>>(v_bf, proj, prior, dscale, mid);

    gemm_out<<<dim3(256, 4), dim3(256), 0, stream>>>(mid, Wt + 576 * 256, out_b, out);
}

// Round 7
// 57.411 us; speedup vs baseline: 1.1434x; 1.0099x over previous
//
#include <hip/hip_runtime.h>
#include <hip/hip_fp16.h>

#define NPIX 16384

typedef __attribute__((ext_vector_type(8))) short short8;
typedef __attribute__((ext_vector_type(8))) _Float16 half8;
typedef __attribute__((ext_vector_type(4))) float f32x4;

__device__ __forceinline__ unsigned short f2bf(float f) {
    unsigned u = __float_as_uint(f);
    unsigned r = (u + 0x7fffu + ((u >> 16) & 1u)) >> 16;
    return (unsigned short)r;
}
__device__ __forceinline__ unsigned short f2h_us(float f) {
    union { _Float16 h; unsigned short u; } cv;
    cv.h = (_Float16)f;
    return cv.u;
}
__device__ __forceinline__ unsigned hdup(float f) {
    unsigned short u = f2h_us(f);
    return (unsigned)u | ((unsigned)u << 16);
}
__device__ __forceinline__ unsigned hfma2u(unsigned w, unsigned v, unsigned a) {
    union { unsigned u; __half2 h; } W, V, A, R;
    W.u = w; V.u = v; A.u = a;
    R.h = __hfma2(W.h, V.h, A.h);
    return R.u;
}
__device__ __forceinline__ unsigned hadd2u(unsigned a, unsigned b) {
    union { unsigned u; __half2 h; } A, B, R;
    A.u = a; B.u = b;
    R.h = __hadd2(A.h, B.h);
    return R.u;
}

#define GLOAD16(SRC, DST) \
    __builtin_amdgcn_global_load_lds( \
        (const __attribute__((address_space(1))) unsigned*)(SRC), \
        (__attribute__((address_space(3))) unsigned*)(DST), 16, 0, 0)

// ---------------------------------------------------------------------------
// prep_all: blocks 0..2047 x->bf16; 2048..2099 Wt transpose; 2100 biasD+pad.
// Wt n-rows: 0-255 v_w | 256-399 qd_w | 400-471 qs_w | 472-543 qw_w |
//            544-575 zero | 576-831 out_w. Rows >=576 stored as F16 (for the
// f16 out-GEMM); rows <576 bf16.
// ---------------------------------------------------------------------------
__device__ __forceinline__ float wsrc(int k, int n,
    const float* v_w, const float* qd_w, const float* qs_w,
    const float* qw_w, const float* out_w)
{
    if (n < 256) return v_w[k * 256 + n];
    n -= 256;
    if (n < 144) return qd_w[k * 144 + n];
    n -= 144;
    if (n < 72)  return qs_w[k * 72 + n];
    n -= 72;
    if (n < 72)  return qw_w[k * 72 + n];
    n -= 72;
    if (n < 32)  return 0.f;
    return out_w[k * 256 + (n - 32)];
}

__global__ __launch_bounds__(256) void prep_all(
    const float* __restrict__ x, unsigned short* __restrict__ xb,
    const float* __restrict__ v_w, const float* __restrict__ qd_w,
    const float* __restrict__ qs_w, const float* __restrict__ qw_w,
    const float* __restrict__ out_w, const float* __restrict__ qd_b,
    const float* __restrict__ qw_b,
    unsigned short* __restrict__ Wt, float* __restrict__ biasD,
    unsigned short* __restrict__ vpad)
{
    __shared__ float t[64][65];
    const int bid = blockIdx.x;
    const int tid = threadIdx.x;

    if (bid < 2048) {
        const size_t i = (size_t)bid * 256 + tid;
        const float4 v0 = *(const float4*)(x + i * 8);
        const float4 v1 = *(const float4*)(x + i * 8 + 4);
        uint4 pk;
        pk.x = f2bf(v0.x) | ((unsigned)f2bf(v0.y) << 16);
        pk.y = f2bf(v0.z) | ((unsigned)f2bf(v0.w) << 16);
        pk.z = f2bf(v1.x) | ((unsigned)f2bf(v1.y) << 16);
        pk.w = f2bf(v1.z) | ((unsigned)f2bf(v1.w) << 16);
        *(uint4*)(xb + i * 8) = pk;
        return;
    }
    if (bid == 2100) {
        for (int i = tid; i < 320; i += 256) {
            float bv = 0.f;
            if (i < 144)                  bv = qd_b[i];
            else if (i >= 216 && i < 288) bv = qw_b[i - 216];
            biasD[i] = bv;
        }
        for (int i = tid; i < 512; i += 256) vpad[i] = 0;  // 1KB guard
        return;
    }
    const int tile = bid - 2048;
    const int tn = tile % 13;
    const int tk = tile / 13;
    #pragma unroll
    for (int i = 0; i < 16; ++i) {
        const int idx = tid + i * 256;
        const int r = idx >> 6;
        const int c = idx & 63;
        t[r][c] = wsrc(tk * 64 + r, tn * 64 + c, v_w, qd_w, qs_w, qw_w, out_w);
    }
    __syncthreads();
    const bool asF16 = (tn >= 9);   // out_w region -> f16
    #pragma unroll
    for (int i = 0; i < 8; ++i) {
        const int idx = tid + i * 256;
        const int rn = idx >> 5;
        const int cc = idx & 31;
        unsigned pk;
        if (asF16)
            pk = (unsigned)f2h_us(t[cc * 2][rn]) | ((unsigned)f2h_us(t[cc * 2 + 1][rn]) << 16);
        else
            pk = (unsigned)f2bf(t[cc * 2][rn]) | ((unsigned)f2bf(t[cc * 2 + 1][rn]) << 16);
        ((unsigned*)(Wt + (size_t)(tn * 64 + rn) * 256 + tk * 64))[cc] = pk;
    }
}

// ---------------------------------------------------------------------------
// gemm_proj: [NPIX][256]bf16 @ Wt[j*64..][256]^T, j=0..8.
//   j<4  -> v_bf F16 GROUP-MAJOR [b][g][4096][32];  j>=4 -> proj f32 [NPIX][320]
// ---------------------------------------------------------------------------
__global__ __launch_bounds__(256) void gemm_proj(
    const unsigned short* __restrict__ A, const unsigned short* __restrict__ Wt,
    const float* __restrict__ v_b, const float* __restrict__ biasD,
    unsigned short* __restrict__ v_bf, float* __restrict__ proj)
{
    __shared__ unsigned short As[64 * 256];
    __shared__ unsigned short Bs[64 * 256];

    const int tid  = threadIdx.x;
    const int wid  = tid >> 6;
    const int lane = tid & 63;
    const int row0 = blockIdx.x * 64;
    const int j    = blockIdx.y;

    const unsigned short* Ab = A  + (size_t)row0 * 256;
    const unsigned short* Bb = Wt + (size_t)(j * 64) * 256;
    const int rl = lane >> 5;
    const int gl = lane & 31;

    #pragma unroll
    for (int it = 0; it < 8; ++it) {
        const int r   = wid * 16 + it * 2 + rl;
        const int gsw = gl ^ (r & 7);
        GLOAD16(Ab + r * 256 + gsw * 8, &As[(wid * 16 + it * 2) * 256]);
        GLOAD16(Bb + r * 256 + gsw * 8, &Bs[(wid * 16 + it * 2) * 256]);
    }
    asm volatile("s_waitcnt vmcnt(0)" ::: "memory");
    __syncthreads();

    f32x4 acc00 = {0,0,0,0}, acc01 = {0,0,0,0};
    f32x4 acc10 = {0,0,0,0}, acc11 = {0,0,0,0};

    const int wr = (wid >> 1) * 32;
    const int wc = (wid & 1) * 32;
    const int fr = lane & 15;
    const int fg = lane >> 4;

    const int ra0 = wr + fr, ra1 = ra0 + 16;
    const int rb0 = wc + fr, rb1 = rb0 + 16;
    const int sa  = ra0 & 7;
    const int sb  = rb0 & 7;

    #pragma unroll
    for (int t = 0; t < 8; ++t) {
        const int gran = t * 4 + fg;
        short8 a0 = *(const short8*)&As[ra0 * 256 + (gran ^ sa) * 8];
        short8 a1 = *(const short8*)&As[ra1 * 256 + (gran ^ sa) * 8];
        short8 b0 = *(const short8*)&Bs[rb0 * 256 + (gran ^ sb) * 8];
        short8 b1 = *(const short8*)&Bs[rb1 * 256 + (gran ^ sb) * 8];
        acc00 = __builtin_amdgcn_mfma_f32_16x16x32_bf16(a0, b0, acc00, 0, 0, 0);
        acc01 = __builtin_amdgcn_mfma_f32_16x16x32_bf16(a0, b1, acc01, 0, 0, 0);
        acc10 = __builtin_amdgcn_mfma_f32_16x16x32_bf16(a1, b0, acc10, 0, 0, 0);
        acc11 = __builtin_amdgcn_mfma_f32_16x16x32_bf16(a1, b1, acc11, 0, 0, 0);
    }

    if (j < 4) {
        const int colA = j * 64 + wc + fr;
        const int colB = colA + 16;
        const int gA = colA >> 5, cA = colA & 31;
        const int gB = colB >> 5, cB = colB & 31;
        const float biasA = v_b[colA];
        const float biasB = v_b[colB];
        #pragma unroll
        for (int jj = 0; jj < 4; ++jj) {
            const int r0a = row0 + wr + fg * 4 + jj;
            const int r1a = r0a + 16;
            const int b0i = r0a >> 12;
            const int hw0 = r0a & 4095, hw1 = r1a & 4095;
            v_bf[((size_t)(b0i * 8 + gA) * 4096 + hw0) * 32 + cA] = f2h_us(acc00[jj] + biasA);
            v_bf[((size_t)(b0i * 8 + gB) * 4096 + hw0) * 32 + cB] = f2h_us(acc01[jj] + biasB);
            v_bf[((size_t)(b0i * 8 + gA) * 4096 + hw1) * 32 + cA] = f2h_us(acc10[jj] + biasA);
            v_bf[((size_t)(b0i * 8 + gB) * 4096 + hw1) * 32 + cB] = f2h_us(acc11[jj] + biasB);
        }
    } else {
        const int colA = (j - 4) * 64 + wc + fr;
        const int colB = colA + 16;
        const float biasA = biasD[colA];
        const float biasB = biasD[colB];
        #pragma unroll
        for (int jj = 0; jj < 4; ++jj) {
            const int r0a = row0 + wr + fg * 4 + jj;
            const int r1a = r0a + 16;
            proj[(size_t)r0a * 320 + colA] = acc00[jj] + biasA;
            proj[(size_t)r0a * 320 + colB] = acc01[jj] + biasB;
            proj[(size_t)r1a * 320 + colA] = acc10[jj] + biasA;
            proj[(size_t)r1a * 320 + colB] = acc11[jj] + biasB;
        }
    }
}

// ---------------------------------------------------------------------------
// gemm_out: out[M][256] = mid[M][256](f16) @ WtO(f16)^T + out_b (f32 out).
// ---------------------------------------------------------------------------
__global__ __launch_bounds__(256) void gemm_out(
    const unsigned short* __restrict__ A, const unsigned short* __restrict__ WtO,
    const float* __restrict__ bias, float* __restrict__ Y)
{
    __shared__ unsigned short As[64 * 256];
    __shared__ unsigned short Bs[64 * 256];

    const int tid  = threadIdx.x;
    const int wid  = tid >> 6;
    const int lane = tid & 63;
    const int row0 = blockIdx.x * 64;
    const int col0 = blockIdx.y * 64;

    const unsigned short* Ab = A   + (size_t)row0 * 256;
    const unsigned short* Bb = WtO + (size_t)col0 * 256;
    const int rl = lane >> 5;
    const int gl = lane & 31;

    #pragma unroll
    for (int it = 0; it < 8; ++it) {
        const int r   = wid * 16 + it * 2 + rl;
        const int gsw = gl ^ (r & 7);
        GLOAD16(Ab + r * 256 + gsw * 8, &As[(wid * 16 + it * 2) * 256]);
        GLOAD16(Bb + r * 256 + gsw * 8, &Bs[(wid * 16 + it * 2) * 256]);
    }
    asm volatile("s_waitcnt vmcnt(0)" ::: "memory");
    __syncthreads();

    f32x4 acc00 = {0,0,0,0}, acc01 = {0,0,0,0};
    f32x4 acc10 = {0,0,0,0}, acc11 = {0,0,0,0};

    const int wr = (wid >> 1) * 32;
    const int wc = (wid & 1) * 32;
    const int fr = lane & 15;
    const int fg = lane >> 4;

    const int ra0 = wr + fr, ra1 = ra0 + 16;
    const int rb0 = wc + fr, rb1 = rb0 + 16;
    const int sa  = ra0 & 7;
    const int sb  = rb0 & 7;

    #pragma unroll
    for (int t = 0; t < 8; ++t) {
        const int gran = t * 4 + fg;
        half8 a0 = *(const half8*)&As[ra0 * 256 + (gran ^ sa) * 8];
        half8 a1 = *(const half8*)&As[ra1 * 256 + (gran ^ sa) * 8];
        half8 b0 = *(const half8*)&Bs[rb0 * 256 + (gran ^ sb) * 8];
        half8 b1 = *(const half8*)&Bs[rb1 * 256 + (gran ^ sb) * 8];
        acc00 = __builtin_amdgcn_mfma_f32_16x16x32_f16(a0, b0, acc00, 0, 0, 0);
        acc01 = __builtin_amdgcn_mfma_f32_16x16x32_f16(a0, b1, acc01, 0, 0, 0);
        acc10 = __builtin_amdgcn_mfma_f32_16x16x32_f16(a1, b0, acc10, 0, 0, 0);
        acc11 = __builtin_amdgcn_mfma_f32_16x16x32_f16(a1, b1, acc11, 0, 0, 0);
    }

    const int colA = col0 + wc + fr;
    const int colB = colA + 16;
    const float biasA = bias[colA];
    const float biasB = bias[colB];
    #pragma unroll
    for (int jj = 0; jj < 4; ++jj) {
        const int r0a = row0 + wr + fg * 4 + jj;
        const int r1a = r0a + 16;
        Y[(size_t)r0a * 256 + colA] = acc00[jj] + biasA;
        Y[(size_t)r0a * 256 + colB] = acc01[jj] + biasB;
        Y[(size_t)r1a * 256 + colA] = acc10[jj] + biasA;
        Y[(size_t)r1a * 256 + colB] = acc11[jj] + biasB;
    }
}

// ---------------------------------------------------------------------------
// Sampler v6: 8 pixels/block, 256 threads; 8 lanes per (pixel,group); each
// thread handles TWO (p,g) pairs (p4 and p4+4) for ILP.
// Phase 1 packs per-tap weights as duplicated half2 (zeroed when invalid).
// Phase 2: per k, 2x 16B gathers + 8 v_pk_fma_f16 -- NO unpack instructions.
// Two accumulator chains (y0/y1) merged in f16; __shfl_xor(4) merges x0/x1.
// ---------------------------------------------------------------------------
__global__ __launch_bounds__(256) void dcn_sample6(
    const unsigned short* __restrict__ vbuf,  // [4][8][4096][32] f16
    const float* __restrict__ proj,           // [NPIX][320]
    const float* __restrict__ prior,          // [K][2]
    const float* __restrict__ dscale,         // [G]
    unsigned short* __restrict__ mid)         // [NPIX][256] f16
{
    __shared__ float    projs[8 * 320];
    __shared__ int      offs[576 * 2];
    __shared__ unsigned wpk [576 * 4];   // duplicated half2 weights

    const int tid = threadIdx.x;
    // bijective XCD swizzle: 2048 blocks = 8 XCDs x 256 contiguous chunks
    const int bid  = blockIdx.x;
    const int wg   = (bid & 7) * 256 + (bid >> 3);
    const int pix0 = wg * 8;

    for (int i = tid; i < 640; i += 256) {
        const int p = i / 80, c = i - p * 80;
        *(float4*)&projs[p * 320 + c * 4] =
            *(const float4*)&proj[(size_t)(pix0 + p) * 320 + c * 4];
    }
    __syncthreads();

    for (int it = tid; it < 576; it += 256) {
        const int p   = it / 72;
        const int rem = it - p * 72;
        const int g   = rem / 9;
        const int k   = rem - g * 9;
        const int pix = pix0 + p;
        const int b   = pix >> 12;
        const int hw  = pix & 4095;
        const int h   = hw >> 6, w = hw & 63;

        const float* row = &projs[p * 320];
        const float qdx = row[g * 18 + k * 2 + 0];
        const float qdy = row[g * 18 + k * 2 + 1];
        const float s   = row[144 + g * 9 + k] + dscale[g];
        const float wt  = row[216 + g * 9 + k];
        const float sig6 = 6.0f / (1.0f + __expf(-s));
        const float px = (float)w + (qdx + prior[k * 2 + 0]) * sig6;
        const float py = (float)h + (qdy + prior[k * 2 + 1]) * sig6;

        const float x0f = floorf(px), y0f = floorf(py);
        const int ix = (int)x0f, iy = (int)y0f;
        const float wx1 = px - x0f, wx0 = 1.f - wx1;
        const float wy1 = py - y0f, wy0 = 1.f - wy1;
        const int plane = (b * 8 + g) << 12;

        const bool vy0 = (iy >= 0) & (iy < 64);
        const bool vy1 = (iy >= -1) & (iy < 63);
        const bool vx0 = (ix >= 0) & (ix < 64);
        const bool vx1 = (ix >= -1) & (ix < 63);
        const float w00 = (vy0 & vx0) ? wt * wy0 * wx0 : 0.f;
        const float w10 = (vy1 & vx0) ? wt * wy1 * wx0 : 0.f;
        const float w01 = (vy0 & vx1) ? wt * wy0 * wx1 : 0.f;
        const float w11 = (vy1 & vx1) ? wt * wy1 * wx1 : 0.f;
        // xh=0 lanes use [0]=w(y0,x0), [1]=w(y1,x0); xh=1: [2],[3]
        wpk[it * 4 + 0] = hdup(w00);
        wpk[it * 4 + 1] = hdup(w10);
        wpk[it * 4 + 2] = hdup(w01);
        wpk[it * 4 + 3] = hdup(w11);

        const int xs  = min(max(ix,     -1), 63);
        const int y0c = min(max(iy,      0), 63);
        const int y1c = min(max(iy + 1,  0), 63);
        offs[it * 2 + 0] = (plane + y0c * 64 + xs) * 64;   // BYTE offsets
        offs[it * 2 + 1] = (plane + y1c * 64 + xs) * 64;
    }
    __syncthreads();

    const int p4 = tid >> 6;          // 0..3 -> pairs (p4, p4+4)
    const int g  = (tid >> 3) & 7;
    const int q  = tid & 7;
    const int xh = q >> 2;
    const int qb = q * 16;            // byte offset: xh*64 + (q&3)*16
    const char* vbb = (const char*)vbuf;

    unsigned aA0=0,aA1=0,aA2=0,aA3=0, aB0=0,aB1=0,aB2=0,aB3=0;   // pair 0
    unsigned bA0=0,bA1=0,bA2=0,bA3=0, bB0=0,bB1=0,bB2=0,bB3=0;   // pair 1
    const int item0a = p4 * 72 + g * 9;
    const int item0b = (p4 + 4) * 72 + g * 9;

    #pragma unroll
    for (int k = 0; k < 9; ++k) {
        {
            const int it = item0a + k;
            const int2  o2 = *(const int2*)&offs[it * 2];
            const uint2 wp = *(const uint2*)&wpk[it * 4 + xh * 2];
            const uint4 r0 = *(const uint4*)(vbb + o2.x + qb);
            const uint4 r1 = *(const uint4*)(vbb + o2.y + qb);
            aA0 = hfma2u(wp.x, r0.x, aA0);
            aA1 = hfma2u(wp.x, r0.y, aA1);
            aA2 = hfma2u(wp.x, r0.z, aA2);
            aA3 = hfma2u(wp.x, r0.w, aA3);
            aB0 = hfma2u(wp.y, r1.x, aB0);
            aB1 = hfma2u(wp.y, r1.y, aB1);
            aB2 = hfma2u(wp.y, r1.z, aB2);
            aB3 = hfma2u(wp.y, r1.w, aB3);
        }
        {
            const int it = item0b + k;
            const int2  o2 = *(const int2*)&offs[it * 2];
            const uint2 wp = *(const uint2*)&wpk[it * 4 + xh * 2];
            const uint4 r0 = *(const uint4*)(vbb + o2.x + qb);
            const uint4 r1 = *(const uint4*)(vbb + o2.y + qb);
            bA0 = hfma2u(wp.x, r0.x, bA0);
            bA1 = hfma2u(wp.x, r0.y, bA1);
            bA2 = hfma2u(wp.x, r0.z, bA2);
            bA3 = hfma2u(wp.x, r0.w, bA3);
            bB0 = hfma2u(wp.y, r1.x, bB0);
            bB1 = hfma2u(wp.y, r1.y, bB1);
            bB2 = hfma2u(wp.y, r1.z, bB2);
            bB3 = hfma2u(wp.y, r1.w, bB3);
        }
    }

    // merge y-chains, then x0/x0+1 partials (lanes q and q^4), store xh==0
    uint4 oA, oB;
    {
        unsigned c;
        c = hadd2u(aA0, aB0); c = hadd2u(c, (unsigned)__shfl_xor((int)c, 4)); oA.x = c;
        c = hadd2u(aA1, aB1); c = hadd2u(c, (unsigned)__shfl_xor((int)c, 4)); oA.y = c;
        c = hadd2u(aA2, aB2); c = hadd2u(c, (unsigned)__shfl_xor((int)c, 4)); oA.z = c;
        c = hadd2u(aA3, aB3); c = hadd2u(c, (unsigned)__shfl_xor((int)c, 4)); oA.w = c;
        c = hadd2u(bA0, bB0); c = hadd2u(c, (unsigned)__shfl_xor((int)c, 4)); oB.x = c;
        c = hadd2u(bA1, bB1); c = hadd2u(c, (unsigned)__shfl_xor((int)c, 4)); oB.y = c;
        c = hadd2u(bA2, bB2); c = hadd2u(c, (unsigned)__shfl_xor((int)c, 4)); oB.z = c;
        c = hadd2u(bA3, bB3); c = hadd2u(c, (unsigned)__shfl_xor((int)c, 4)); oB.w = c;
    }
    if (xh == 0) {
        const int cq8 = (q & 3) * 8;
        *(uint4*)(mid + (size_t)(pix0 + p4) * 256 + g * 32 + cq8) = oA;
        *(uint4*)(mid + (size_t)(pix0 + p4 + 4) * 256 + g * 32 + cq8) = oB;
    }
}

// ---------------------------------------------------------------------------
extern "C" void kernel_launch(void* const* d_in, const int* in_sizes, int n_in,
                              void* d_out, int out_size, void* d_ws, size_t ws_size,
                              hipStream_t stream)
{
    (void)in_sizes; (void)n_in; (void)out_size; (void)ws_size;

    const float* x      = (const float*)d_in[0];
    const float* v_w    = (const float*)d_in[1];
    const float* v_b    = (const float*)d_in[2];
    const float* qd_w   = (const float*)d_in[3];
    const float* qd_b   = (const float*)d_in[4];
    const float* qs_w   = (const float*)d_in[5];
    const float* qw_w   = (const float*)d_in[6];
    const float* qw_b   = (const float*)d_in[7];
    const float* out_w  = (const float*)d_in[8];
    const float* out_b  = (const float*)d_in[9];
    const float* prior  = (const float*)d_in[10];
    const float* dscale = (const float*)d_in[11];
    float* out = (float*)d_out;

    char* ws = (char*)d_ws;
    unsigned short* xb    = (unsigned short*)(ws);                    // 8 MB
    unsigned short* v_bf  = (unsigned short*)(ws + 8388608);          // 8 MB (f16)
    unsigned short* vpad  = (unsigned short*)(ws + 16777216);         // 1 KB guard
    float*          proj  = (float*)(ws + 16778240);                  // ~21 MB
    unsigned short* mid   = (unsigned short*)(ws + 37749760);         // 8 MB (f16)
    unsigned short* Wt    = (unsigned short*)(ws + 46138368);         // 416 KB
    float*          biasD = (float*)(ws + 46564352);                  // 1.25 KB

    prep_all<<<dim3(2101), dim3(256), 0, stream>>>(x, xb, v_w, qd_w, qs_w, qw_w,
                                                   out_w, qd_b, qw_b, Wt, biasD, vpad);

    gemm_proj<<<dim3(256, 9), dim3(256), 0, stream>>>(xb, Wt, v_b, biasD, v_bf, proj);

    dcn_sample6<<<dim3(NPIX / 8), dim3(256), 0, stream>>>(v_bf, proj, prior, dscale, mid);

    gemm_out<<<dim3(256, 4), dim3(256), 0, stream>>>(mid, Wt + 576 * 256, out_b, out);
}

// Round 8
// 57.115 us; speedup vs baseline: 1.1494x; 1.0052x over previous
//
#include <hip/hip_runtime.h>
#include <hip/hip_fp16.h>

#define NPIX 16384

typedef __attribute__((ext_vector_type(8))) short short8;
typedef __attribute__((ext_vector_type(8))) _Float16 half8;
typedef __attribute__((ext_vector_type(4))) float f32x4;

__device__ __forceinline__ unsigned short f2bf(float f) {
    unsigned u = __float_as_uint(f);
    unsigned r = (u + 0x7fffu + ((u >> 16) & 1u)) >> 16;
    return (unsigned short)r;
}
__device__ __forceinline__ unsigned short f2h_us(float f) {
    union { _Float16 h; unsigned short u; } cv;
    cv.h = (_Float16)f;
    return cv.u;
}
__device__ __forceinline__ unsigned hdup(float f) {
    unsigned short u = f2h_us(f);
    return (unsigned)u | ((unsigned)u << 16);
}
__device__ __forceinline__ unsigned hfma2u(unsigned w, unsigned v, unsigned a) {
    union { unsigned u; __half2 h; } W, V, A, R;
    W.u = w; V.u = v; A.u = a;
    R.h = __hfma2(W.h, V.h, A.h);
    return R.u;
}
__device__ __forceinline__ unsigned hadd2u(unsigned a, unsigned b) {
    union { unsigned u; __half2 h; } A, B, R;
    A.u = a; B.u = b;
    R.h = __hadd2(A.h, B.h);
    return R.u;
}

#define GLOAD16(SRC, DST) \
    __builtin_amdgcn_global_load_lds( \
        (const __attribute__((address_space(1))) unsigned*)(SRC), \
        (__attribute__((address_space(3))) unsigned*)(DST), 16, 0, 0)

// XCD-alignment convention (8 XCDs, flat-id round-robin => xcd = flat & 7):
//   XCD e owns pixels [e*2048, (e+1)*2048).
//   prep x-blocks (8 px each):  b' = (b>>3) + (b&7)*256
//   64-px row-tiles (gemms):    t  = (bx>>3) + (bx&7)*32   (gridDim.x=256, %8==0)
//   sampler (8 px blocks):      wg = (bid&7)*256 + (bid>>3)
// All producers/consumers of v_bf / proj / mid / xb then touch the same L2.

// ---------------------------------------------------------------------------
// prep_all: blocks 0..2047 x->bf16 (XCD-aligned); 2048..2099 Wt transpose;
// 2100 biasD+pad. Wt n-rows: 0-255 v_w | 256-399 qd_w | 400-471 qs_w |
// 472-543 qw_w | 544-575 zero | 576-831 out_w (f16; rest bf16).
// ---------------------------------------------------------------------------
__device__ __forceinline__ float wsrc(int k, int n,
    const float* v_w, const float* qd_w, const float* qs_w,
    const float* qw_w, const float* out_w)
{
    if (n < 256) return v_w[k * 256 + n];
    n -= 256;
    if (n < 144) return qd_w[k * 144 + n];
    n -= 144;
    if (n < 72)  return qs_w[k * 72 + n];
    n -= 72;
    if (n < 72)  return qw_w[k * 72 + n];
    n -= 72;
    if (n < 32)  return 0.f;
    return out_w[k * 256 + (n - 32)];
}

__global__ __launch_bounds__(256) void prep_all(
    const float* __restrict__ x, unsigned short* __restrict__ xb,
    const float* __restrict__ v_w, const float* __restrict__ qd_w,
    const float* __restrict__ qs_w, const float* __restrict__ qw_w,
    const float* __restrict__ out_w, const float* __restrict__ qd_b,
    const float* __restrict__ qw_b,
    unsigned short* __restrict__ Wt, float* __restrict__ biasD,
    unsigned short* __restrict__ vpad)
{
    __shared__ float t[64][65];
    const int bid = blockIdx.x;
    const int tid = threadIdx.x;

    if (bid < 2048) {
        const int bb = (bid >> 3) + (bid & 7) * 256;   // XCD-aligned pixel range
        const size_t i = (size_t)bb * 256 + tid;
        const float4 v0 = *(const float4*)(x + i * 8);
        const float4 v1 = *(const float4*)(x + i * 8 + 4);
        uint4 pk;
        pk.x = f2bf(v0.x) | ((unsigned)f2bf(v0.y) << 16);
        pk.y = f2bf(v0.z) | ((unsigned)f2bf(v0.w) << 16);
        pk.z = f2bf(v1.x) | ((unsigned)f2bf(v1.y) << 16);
        pk.w = f2bf(v1.z) | ((unsigned)f2bf(v1.w) << 16);
        *(uint4*)(xb + i * 8) = pk;
        return;
    }
    if (bid == 2100) {
        for (int i = tid; i < 320; i += 256) {
            float bv = 0.f;
            if (i < 144)                  bv = qd_b[i];
            else if (i >= 216 && i < 288) bv = qw_b[i - 216];
            biasD[i] = bv;
        }
        for (int i = tid; i < 512; i += 256) vpad[i] = 0;  // 1KB guard
        return;
    }
    const int tile = bid - 2048;
    const int tn = tile % 13;
    const int tk = tile / 13;
    #pragma unroll
    for (int i = 0; i < 16; ++i) {
        const int idx = tid + i * 256;
        const int r = idx >> 6;
        const int c = idx & 63;
        t[r][c] = wsrc(tk * 64 + r, tn * 64 + c, v_w, qd_w, qs_w, qw_w, out_w);
    }
    __syncthreads();
    const bool asF16 = (tn >= 9);   // out_w region -> f16
    #pragma unroll
    for (int i = 0; i < 8; ++i) {
        const int idx = tid + i * 256;
        const int rn = idx >> 5;
        const int cc = idx & 31;
        unsigned pk;
        if (asF16)
            pk = (unsigned)f2h_us(t[cc * 2][rn]) | ((unsigned)f2h_us(t[cc * 2 + 1][rn]) << 16);
        else
            pk = (unsigned)f2bf(t[cc * 2][rn]) | ((unsigned)f2bf(t[cc * 2 + 1][rn]) << 16);
        ((unsigned*)(Wt + (size_t)(tn * 64 + rn) * 256 + tk * 64))[cc] = pk;
    }
}

// ---------------------------------------------------------------------------
// gemm_proj: [NPIX][256]bf16 @ Wt[j*64..][256]^T, j=0..8. Row-tiles
// XCD-remapped so v_bf/proj rows are produced in the consumer's L2.
//   j<4  -> v_bf F16 GROUP-MAJOR [b][g][4096][32];  j>=4 -> proj f32 [NPIX][320]
// ---------------------------------------------------------------------------
__global__ __launch_bounds__(256) void gemm_proj(
    const unsigned short* __restrict__ A, const unsigned short* __restrict__ Wt,
    const float* __restrict__ v_b, const float* __restrict__ biasD,
    unsigned short* __restrict__ v_bf, float* __restrict__ proj)
{
    __shared__ unsigned short As[64 * 256];
    __shared__ unsigned short Bs[64 * 256];

    const int tid  = threadIdx.x;
    const int wid  = tid >> 6;
    const int lane = tid & 63;
    const int bx   = blockIdx.x;
    const int tile = (bx >> 3) + (bx & 7) * 32;     // XCD-aligned row tile
    const int row0 = tile * 64;
    const int j    = blockIdx.y;

    const unsigned short* Ab = A  + (size_t)row0 * 256;
    const unsigned short* Bb = Wt + (size_t)(j * 64) * 256;
    const int rl = lane >> 5;
    const int gl = lane & 31;

    #pragma unroll
    for (int it = 0; it < 8; ++it) {
        const int r   = wid * 16 + it * 2 + rl;
        const int gsw = gl ^ (r & 7);
        GLOAD16(Ab + r * 256 + gsw * 8, &As[(wid * 16 + it * 2) * 256]);
        GLOAD16(Bb + r * 256 + gsw * 8, &Bs[(wid * 16 + it * 2) * 256]);
    }
    asm volatile("s_waitcnt vmcnt(0)" ::: "memory");
    __syncthreads();

    f32x4 acc00 = {0,0,0,0}, acc01 = {0,0,0,0};
    f32x4 acc10 = {0,0,0,0}, acc11 = {0,0,0,0};

    const int wr = (wid >> 1) * 32;
    const int wc = (wid & 1) * 32;
    const int fr = lane & 15;
    const int fg = lane >> 4;

    const int ra0 = wr + fr, ra1 = ra0 + 16;
    const int rb0 = wc + fr, rb1 = rb0 + 16;
    const int sa  = ra0 & 7;
    const int sb  = rb0 & 7;

    #pragma unroll
    for (int t = 0; t < 8; ++t) {
        const int gran = t * 4 + fg;
        short8 a0 = *(const short8*)&As[ra0 * 256 + (gran ^ sa) * 8];
        short8 a1 = *(const short8*)&As[ra1 * 256 + (gran ^ sa) * 8];
        short8 b0 = *(const short8*)&Bs[rb0 * 256 + (gran ^ sb) * 8];
        short8 b1 = *(const short8*)&Bs[rb1 * 256 + (gran ^ sb) * 8];
        acc00 = __builtin_amdgcn_mfma_f32_16x16x32_bf16(a0, b0, acc00, 0, 0, 0);
        acc01 = __builtin_amdgcn_mfma_f32_16x16x32_bf16(a0, b1, acc01, 0, 0, 0);
        acc10 = __builtin_amdgcn_mfma_f32_16x16x32_bf16(a1, b0, acc10, 0, 0, 0);
        acc11 = __builtin_amdgcn_mfma_f32_16x16x32_bf16(a1, b1, acc11, 0, 0, 0);
    }

    if (j < 4) {
        const int colA = j * 64 + wc + fr;
        const int colB = colA + 16;
        const int gA = colA >> 5, cA = colA & 31;
        const int gB = colB >> 5, cB = colB & 31;
        const float biasA = v_b[colA];
        const float biasB = v_b[colB];
        #pragma unroll
        for (int jj = 0; jj < 4; ++jj) {
            const int r0a = row0 + wr + fg * 4 + jj;
            const int r1a = r0a + 16;
            const int b0i = r0a >> 12;
            const int hw0 = r0a & 4095, hw1 = r1a & 4095;
            v_bf[((size_t)(b0i * 8 + gA) * 4096 + hw0) * 32 + cA] = f2h_us(acc00[jj] + biasA);
            v_bf[((size_t)(b0i * 8 + gB) * 4096 + hw0) * 32 + cB] = f2h_us(acc01[jj] + biasB);
            v_bf[((size_t)(b0i * 8 + gA) * 4096 + hw1) * 32 + cA] = f2h_us(acc10[jj] + biasA);
            v_bf[((size_t)(b0i * 8 + gB) * 4096 + hw1) * 32 + cB] = f2h_us(acc11[jj] + biasB);
        }
    } else {
        const int colA = (j - 4) * 64 + wc + fr;
        const int colB = colA + 16;
        const float biasA = biasD[colA];
        const float biasB = biasD[colB];
        #pragma unroll
        for (int jj = 0; jj < 4; ++jj) {
            const int r0a = row0 + wr + fg * 4 + jj;
            const int r1a = r0a + 16;
            proj[(size_t)r0a * 320 + colA] = acc00[jj] + biasA;
            proj[(size_t)r0a * 320 + colB] = acc01[jj] + biasB;
            proj[(size_t)r1a * 320 + colA] = acc10[jj] + biasA;
            proj[(size_t)r1a * 320 + colB] = acc11[jj] + biasB;
        }
    }
}

// ---------------------------------------------------------------------------
// gemm_out: out[M][256] = mid[M][256](f16) @ WtO(f16)^T + out_b (f32 out).
// Row-tiles XCD-remapped to match the sampler's mid placement.
// ---------------------------------------------------------------------------
__global__ __launch_bounds__(256) void gemm_out(
    const unsigned short* __restrict__ A, const unsigned short* __restrict__ WtO,
    const float* __restrict__ bias, float* __restrict__ Y)
{
    __shared__ unsigned short As[64 * 256];
    __shared__ unsigned short Bs[64 * 256];

    const int tid  = threadIdx.x;
    const int wid  = tid >> 6;
    const int lane = tid & 63;
    const int bx   = blockIdx.x;
    const int tile = (bx >> 3) + (bx & 7) * 32;     // XCD-aligned row tile
    const int row0 = tile * 64;
    const int col0 = blockIdx.y * 64;

    const unsigned short* Ab = A   + (size_t)row0 * 256;
    const unsigned short* Bb = WtO + (size_t)col0 * 256;
    const int rl = lane >> 5;
    const int gl = lane & 31;

    #pragma unroll
    for (int it = 0; it < 8; ++it) {
        const int r   = wid * 16 + it * 2 + rl;
        const int gsw = gl ^ (r & 7);
        GLOAD16(Ab + r * 256 + gsw * 8, &As[(wid * 16 + it * 2) * 256]);
        GLOAD16(Bb + r * 256 + gsw * 8, &Bs[(wid * 16 + it * 2) * 256]);
    }
    asm volatile("s_waitcnt vmcnt(0)" ::: "memory");
    __syncthreads();

    f32x4 acc00 = {0,0,0,0}, acc01 = {0,0,0,0};
    f32x4 acc10 = {0,0,0,0}, acc11 = {0,0,0,0};

    const int wr = (wid >> 1) * 32;
    const int wc = (wid & 1) * 32;
    const int fr = lane & 15;
    const int fg = lane >> 4;

    const int ra0 = wr + fr, ra1 = ra0 + 16;
    const int rb0 = wc + fr, rb1 = rb0 + 16;
    const int sa  = ra0 & 7;
    const int sb  = rb0 & 7;

    #pragma unroll
    for (int t = 0; t < 8; ++t) {
        const int gran = t * 4 + fg;
        half8 a0 = *(const half8*)&As[ra0 * 256 + (gran ^ sa) * 8];
        half8 a1 = *(const half8*)&As[ra1 * 256 + (gran ^ sa) * 8];
        half8 b0 = *(const half8*)&Bs[rb0 * 256 + (gran ^ sb) * 8];
        half8 b1 = *(const half8*)&Bs[rb1 * 256 + (gran ^ sb) * 8];
        acc00 = __builtin_amdgcn_mfma_f32_16x16x32_f16(a0, b0, acc00, 0, 0, 0);
        acc01 = __builtin_amdgcn_mfma_f32_16x16x32_f16(a0, b1, acc01, 0, 0, 0);
        acc10 = __builtin_amdgcn_mfma_f32_16x16x32_f16(a1, b0, acc10, 0, 0, 0);
        acc11 = __builtin_amdgcn_mfma_f32_16x16x32_f16(a1, b1, acc11, 0, 0, 0);
    }

    const int colA = col0 + wc + fr;
    const int colB = colA + 16;
    const float biasA = bias[colA];
    const float biasB = bias[colB];
    #pragma unroll
    for (int jj = 0; jj < 4; ++jj) {
        const int r0a = row0 + wr + fg * 4 + jj;
        const int r1a = r0a + 16;
        Y[(size_t)r0a * 256 + colA] = acc00[jj] + biasA;
        Y[(size_t)r0a * 256 + colB] = acc01[jj] + biasB;
        Y[(size_t)r1a * 256 + colA] = acc10[jj] + biasA;
        Y[(size_t)r1a * 256 + colB] = acc11[jj] + biasB;
    }
}

// ---------------------------------------------------------------------------
// Sampler v6 (unchanged from round 7): 8 px/block, packed-f16 math, XCD
// swizzle wg=(bid&7)*256+(bid>>3) -- now ALIGNED with producer placement.
// ---------------------------------------------------------------------------
__global__ __launch_bounds__(256) void dcn_sample6(
    const unsigned short* __restrict__ vbuf,  // [4][8][4096][32] f16
    const float* __restrict__ proj,           // [NPIX][320]
    const float* __restrict__ prior,          // [K][2]
    const float* __restrict__ dscale,         // [G]
    unsigned short* __restrict__ mid)         // [NPIX][256] f16
{
    __shared__ float    projs[8 * 320];
    __shared__ int      offs[576 * 2];
    __shared__ unsigned wpk [576 * 4];

    const int tid = threadIdx.x;
    const int bid  = blockIdx.x;
    const int wg   = (bid & 7) * 256 + (bid >> 3);
    const int pix0 = wg * 8;

    for (int i = tid; i < 640; i += 256) {
        const int p = i / 80, c = i - p * 80;
        *(float4*)&projs[p * 320 + c * 4] =
            *(const float4*)&proj[(size_t)(pix0 + p) * 320 + c * 4];
    }
    __syncthreads();

    for (int it = tid; it < 576; it += 256) {
        const int p   = it / 72;
        const int rem = it - p * 72;
        const int g   = rem / 9;
        const int k   = rem - g * 9;
        const int pix = pix0 + p;
        const int b   = pix >> 12;
        const int hw  = pix & 4095;
        const int h   = hw >> 6, w = hw & 63;

        const float* row = &projs[p * 320];
        const float qdx = row[g * 18 + k * 2 + 0];
        const float qdy = row[g * 18 + k * 2 + 1];
        const float s   = row[144 + g * 9 + k] + dscale[g];
        const float wt  = row[216 + g * 9 + k];
        const float sig6 = 6.0f / (1.0f + __expf(-s));
        const float px = (float)w + (qdx + prior[k * 2 + 0]) * sig6;
        const float py = (float)h + (qdy + prior[k * 2 + 1]) * sig6;

        const float x0f = floorf(px), y0f = floorf(py);
        const int ix = (int)x0f, iy = (int)y0f;
        const float wx1 = px - x0f, wx0 = 1.f - wx1;
        const float wy1 = py - y0f, wy0 = 1.f - wy1;
        const int plane = (b * 8 + g) << 12;

        const bool vy0 = (iy >= 0) & (iy < 64);
        const bool vy1 = (iy >= -1) & (iy < 63);
        const bool vx0 = (ix >= 0) & (ix < 64);
        const bool vx1 = (ix >= -1) & (ix < 63);
        const float w00 = (vy0 & vx0) ? wt * wy0 * wx0 : 0.f;
        const float w10 = (vy1 & vx0) ? wt * wy1 * wx0 : 0.f;
        const float w01 = (vy0 & vx1) ? wt * wy0 * wx1 : 0.f;
        const float w11 = (vy1 & vx1) ? wt * wy1 * wx1 : 0.f;
        wpk[it * 4 + 0] = hdup(w00);
        wpk[it * 4 + 1] = hdup(w10);
        wpk[it * 4 + 2] = hdup(w01);
        wpk[it * 4 + 3] = hdup(w11);

        const int xs  = min(max(ix,     -1), 63);
        const int y0c = min(max(iy,      0), 63);
        const int y1c = min(max(iy + 1,  0), 63);
        offs[it * 2 + 0] = (plane + y0c * 64 + xs) * 64;   // BYTE offsets
        offs[it * 2 + 1] = (plane + y1c * 64 + xs) * 64;
    }
    __syncthreads();

    const int p4 = tid >> 6;
    const int g  = (tid >> 3) & 7;
    const int q  = tid & 7;
    const int xh = q >> 2;
    const int qb = q * 16;
    const char* vbb = (const char*)vbuf;

    unsigned aA0=0,aA1=0,aA2=0,aA3=0, aB0=0,aB1=0,aB2=0,aB3=0;
    unsigned bA0=0,bA1=0,bA2=0,bA3=0, bB0=0,bB1=0,bB2=0,bB3=0;
    const int item0a = p4 * 72 + g * 9;
    const int item0b = (p4 + 4) * 72 + g * 9;

    #pragma unroll
    for (int k = 0; k < 9; ++k) {
        {
            const int it = item0a + k;
            const int2  o2 = *(const int2*)&offs[it * 2];
            const uint2 wp = *(const uint2*)&wpk[it * 4 + xh * 2];
            const uint4 r0 = *(const uint4*)(vbb + o2.x + qb);
            const uint4 r1 = *(const uint4*)(vbb + o2.y + qb);
            aA0 = hfma2u(wp.x, r0.x, aA0);
            aA1 = hfma2u(wp.x, r0.y, aA1);
            aA2 = hfma2u(wp.x, r0.z, aA2);
            aA3 = hfma2u(wp.x, r0.w, aA3);
            aB0 = hfma2u(wp.y, r1.x, aB0);
            aB1 = hfma2u(wp.y, r1.y, aB1);
            aB2 = hfma2u(wp.y, r1.z, aB2);
            aB3 = hfma2u(wp.y, r1.w, aB3);
        }
        {
            const int it = item0b + k;
            const int2  o2 = *(const int2*)&offs[it * 2];
            const uint2 wp = *(const uint2*)&wpk[it * 4 + xh * 2];
            const uint4 r0 = *(const uint4*)(vbb + o2.x + qb);
            const uint4 r1 = *(const uint4*)(vbb + o2.y + qb);
            bA0 = hfma2u(wp.x, r0.x, bA0);
            bA1 = hfma2u(wp.x, r0.y, bA1);
            bA2 = hfma2u(wp.x, r0.z, bA2);
            bA3 = hfma2u(wp.x, r0.w, bA3);
            bB0 = hfma2u(wp.y, r1.x, bB0);
            bB1 = hfma2u(wp.y, r1.y, bB1);
            bB2 = hfma2u(wp.y, r1.z, bB2);
            bB3 = hfma2u(wp.y, r1.w, bB3);
        }
    }

    uint4 oA, oB;
    {
        unsigned c;
        c = hadd2u(aA0, aB0); c = hadd2u(c, (unsigned)__shfl_xor((int)c, 4)); oA.x = c;
        c = hadd2u(aA1, aB1); c = hadd2u(c, (unsigned)__shfl_xor((int)c, 4)); oA.y = c;
        c = hadd2u(aA2, aB2); c = hadd2u(c, (unsigned)__shfl_xor((int)c, 4)); oA.z = c;
        c = hadd2u(aA3, aB3); c = hadd2u(c, (unsigned)__shfl_xor((int)c, 4)); oA.w = c;
        c = hadd2u(bA0, bB0); c = hadd2u(c, (unsigned)__shfl_xor((int)c, 4)); oB.x = c;
        c = hadd2u(bA1, bB1); c = hadd2u(c, (unsigned)__shfl_xor((int)c, 4)); oB.y = c;
        c = hadd2u(bA2, bB2); c = hadd2u(c, (unsigned)__shfl_xor((int)c, 4)); oB.z = c;
        c = hadd2u(bA3, bB3); c = hadd2u(c, (unsigned)__shfl_xor((int)c, 4)); oB.w = c;
    }
    if (xh == 0) {
        const int cq8 = (q & 3) * 8;
        *(uint4*)(mid + (size_t)(pix0 + p4) * 256 + g * 32 + cq8) = oA;
        *(uint4*)(mid + (size_t)(pix0 + p4 + 4) * 256 + g * 32 + cq8) = oB;
    }
}

// ---------------------------------------------------------------------------
extern "C" void kernel_launch(void* const* d_in, const int* in_sizes, int n_in,
                              void* d_out, int out_size, void* d_ws, size_t ws_size,
                              hipStream_t stream)
{
    (void)in_sizes; (void)n_in; (void)out_size; (void)ws_size;

    const float* x      = (const float*)d_in[0];
    const float* v_w    = (const float*)d_in[1];
    const float* v_b    = (const float*)d_in[2];
    const float* qd_w   = (const float*)d_in[3];
    const float* qd_b   = (const float*)d_in[4];
    const float* qs_w   = (const float*)d_in[5];
    const float* qw_w   = (const float*)d_in[6];
    const float* qw_b   = (const float*)d_in[7];
    const float* out_w  = (const float*)d_in[8];
    const float* out_b  = (const float*)d_in[9];
    const float* prior  = (const float*)d_in[10];
    const float* dscale = (const float*)d_in[11];
    float* out = (float*)d_out;

    char* ws = (char*)d_ws;
    unsigned short* xb    = (unsigned short*)(ws);                    // 8 MB
    unsigned short* v_bf  = (unsigned short*)(ws + 8388608);          // 8 MB (f16)
    unsigned short* vpad  = (unsigned short*)(ws + 16777216);         // 1 KB guard
    float*          proj  = (float*)(ws + 16778240);                  // ~21 MB
    unsigned short* mid   = (unsigned short*)(ws + 37749760);         // 8 MB (f16)
    unsigned short* Wt    = (unsigned short*)(ws + 46138368);         // 416 KB
    float*          biasD = (float*)(ws + 46564352);                  // 1.25 KB

    prep_all<<<dim3(2101), dim3(256), 0, stream>>>(x, xb, v_w, qd_w, qs_w, qw_w,
                                                   out_w, qd_b, qw_b, Wt, biasD, vpad);

    gemm_proj<<<dim3(256, 9), dim3(256), 0, stream>>>(xb, Wt, v_b, biasD, v_bf, proj);

    dcn_sample6<<<dim3(NPIX / 8), dim3(256), 0, stream>>>(v_bf, proj, prior, dscale, mid);

    gemm_out<<<dim3(256, 4), dim3(256), 0, stream>>>(mid, Wt + 576 * 256, out_b, out);
}